// Round 8
// baseline (968.602 us; speedup 1.0000x reference)
//
#include <hip/hip_runtime.h>
#include <cstddef>
#include <cstdint>

// DynamicGPCM: B=4096 sequences, S=512 steps, D=16, K=5, H=256, IN=37.
// Outputs (f32, concat): theta(B,S,16) | alpha(B,S,16) | beta(B,S,4) | logits(B,S,5) | probs(B,S,5)
//
// R8 = R7 + K-split Phase C:
//  - Phase C: wave w computes gate/delta partial over ITS OWN 64 H-rows (4 MFMA,
//    wave-private H, fence-only) -> 32x16 f32 partial exchange via LDS -> one
//    balanced barrier -> 6 b128 reads + adds. MFMA/wave 24->12, wgdA regs 64->16.
//  - log2-domain logits: precomputed bsC_k = (cumsum beta)_k * log2(e);
//    lC_k = fma(k, z*log2e, -bsC_k) -> 4 independent FMAs feeding exp2 directly.
//  - output stores distributed across waves (balanced barrier arrival):
//    w0 theta, w1 logits(c=g), w2 probs(c=g), w3 c=4 tail.

namespace {
constexpr int Bn = 4096;
constexpr int Sn = 512;
constexpr int Qn = 1000;

constexpr int UST = 144;    // U row stride (bytes)
constexpr int HST = 528;    // H row stride (bytes)
constexpr int PLN = 36;     // partial lane stride (bytes) - bank spread
constexpr int PWV = 64 * PLN;          // 2304 B per wave
constexpr int PBUF = 4 * PWV;          // 9216 B per buffer

constexpr float LOG2E = 1.44269504088896f;
constexpr float LN2 = 0.693147180559945f;

typedef __attribute__((ext_vector_type(8))) __bf16 bf16x8;
typedef __attribute__((ext_vector_type(4))) float f32x4;
typedef __attribute__((ext_vector_type(4))) unsigned short u16x4;

__device__ __forceinline__ float frcp(float x) { return __builtin_amdgcn_rcpf(x); }
__device__ __forceinline__ float fexp2(float x) {
  float r;
  asm("v_exp_f32 %0, %1" : "=v"(r) : "v"(x));
  return r;
}
__device__ __forceinline__ float ftanh(float x) {
  return 1.0f - 2.0f * frcp(fexp2(x * 2.88539008177793f) + 1.0f);
}
__device__ __forceinline__ float fsigmoid(float x) {
  return frcp(1.0f + fexp2(x * -LOG2E));
}
__device__ __forceinline__ float fsoftplus(float x) {
  return (x > 20.0f) ? x : log1pf(__expf(x));
}
__device__ __forceinline__ unsigned short f2b(float x) {
  return __builtin_bit_cast(unsigned short, (__bf16)x);
}
// u-column permutation: U cols = [theta 0-15 | a 16-31 | surprise 32 | beta 33-36]
// W_h rows  = [theta 0-15 | surprise 16 | a 17-32 | beta 33-36]
__device__ __forceinline__ int permk(int k) {
  if (k < 16) return k;
  if (k < 32) return k + 1;
  if (k == 32) return 16;
  return k;
}

#define WAVE_FENCE() asm volatile("s_waitcnt lgkmcnt(0)" ::: "memory")
#define BLOCK_SYNC()                                        \
  do {                                                      \
    asm volatile("s_waitcnt lgkmcnt(0)" ::: "memory");      \
    __builtin_amdgcn_s_barrier();                           \
    asm volatile("" ::: "memory");                          \
  } while (0)

// ---- Kernel A: per-question item parameters ----
__global__ void precompute_kernel(const float* __restrict__ alpha_raw,
                                  const float* __restrict__ beta_base,
                                  const float* __restrict__ beta_gaps,
                                  float* __restrict__ alpha_q,
                                  float* __restrict__ beta_q,
                                  float* __restrict__ bsumC_q) {
  int tid = blockIdx.x * 256 + threadIdx.x;
  if (tid < (Qn + 1) * 16) alpha_q[tid] = __expf(0.3f * alpha_raw[tid]);
  if (tid < Qn + 1) {
    float base = beta_base[tid];
    float sp0 = fsoftplus(beta_gaps[tid * 3 + 0]);
    float sp1 = fsoftplus(beta_gaps[tid * 3 + 1]);
    float sp2 = fsoftplus(beta_gaps[tid * 3 + 2]);
    float b1 = base, b2 = base + sp0, b3 = b2 + sp1, b4 = b3 + sp2;
    beta_q[tid * 4 + 0] = b1;
    beta_q[tid * 4 + 1] = b2;
    beta_q[tid * 4 + 2] = b3;
    beta_q[tid * 4 + 3] = b4;
    // cumulative-of-cumulative, scaled by log2(e): lC_k = k*z*log2e - bsC_k
    float c1 = b1, c2 = c1 + b2, c3 = c2 + b3, c4 = c3 + b4;
    bsumC_q[tid * 4 + 0] = c1 * LOG2E;
    bsumC_q[tid * 4 + 1] = c2 * LOG2E;
    bsumC_q[tid * 4 + 2] = c3 * LOG2E;
    bsumC_q[tid * 4 + 3] = c4 * LOG2E;
  }
}

// ---- Kernel B: gather alpha/beta output tensors ----
__global__ void itemout_kernel(const int* __restrict__ questions,
                               const float4* __restrict__ alpha_q4,
                               const float4* __restrict__ beta_q4,
                               float4* __restrict__ out_alpha4,
                               float4* __restrict__ out_beta4) {
  int tid = blockIdx.x * 256 + threadIdx.x;
  int pos = tid >> 2, j = tid & 3;
  if (pos >= Bn * Sn) return;
  int q = questions[pos];
  out_alpha4[(size_t)pos * 4 + j] = alpha_q4[(size_t)q * 4 + j];
  if (j == 0) out_beta4[pos] = beta_q4[q];
}

// ---- Kernel C: MFMA scan. 256 threads (4 waves), 16 seqs/block, grid 256 ----
__global__ __launch_bounds__(256, 1) void scan_kernel(
    const float* __restrict__ theta_embed,
    const float* __restrict__ W_h, const float* __restrict__ b_h,
    const float* __restrict__ W_g, const float* __restrict__ b_g,
    const float* __restrict__ W_d, const float* __restrict__ b_d,
    const int* __restrict__ student_ids, const int* __restrict__ questions,
    const int* __restrict__ responses,
    const float* __restrict__ alpha_q, const float4* __restrict__ beta_q4,
    const float4* __restrict__ bsumC_q4,
    float* __restrict__ out_theta, float* __restrict__ out_logits,
    float* __restrict__ out_probs) {
  __shared__ char sU[4 * 16 * UST];   // per-wave U^T: [16 s][64 k] bf16
  __shared__ char sH[16 * HST];       // H: [16 s][256 j] bf16; wave-private 128B chunks
  __shared__ char sP[2 * PBUF];       // gate/delta partials, dbuf

  const int tid = threadIdx.x;
  const int lane = tid & 63;
  const int wv = tid >> 6;        // 0..3
  const int s = lane & 15;        // seq slot / MFMA N-col
  const int g = lane >> 4;        // quad group
  const int bs = blockIdx.x * 16 + s;

  char* uB = sU + wv * (16 * UST);
  {  // zero the used 128B of each U row (pad cols 37..63 stay 0 forever)
    int4 zz = {0, 0, 0, 0};
    char* p = uB + (lane >> 2) * UST + (lane & 3) * 32;
    *(int4*)p = zz;
    *(int4*)(p + 16) = zz;
  }

  // ---- A-fragments: Wh^T slice for this wave's 64 j-rows ----
  bf16x8 whA[4][2];
#pragma unroll
  for (int m = 0; m < 4; ++m) {
    const int j = 64 * wv + 16 * m + s;
#pragma unroll
    for (int kk = 0; kk < 2; ++kk) {
#pragma unroll
      for (int e = 0; e < 8; ++e) {
        const int k = kk * 32 + g * 8 + e;
        float v = 0.0f;
        if (k < 37) v = W_h[permk(k) * 256 + j];
        whA[m][kk][e] = (__bf16)v;
      }
    }
  }
  // ---- A-fragments: [Wg^T ; Wd^T] K-slice for this wave (k = 64wv..64wv+63) ----
  bf16x8 wgdA[2][2];
#pragma unroll
  for (int m = 0; m < 2; ++m) {
    const float* Wm = m ? W_d : W_g;
#pragma unroll
    for (int kk = 0; kk < 2; ++kk) {
#pragma unroll
      for (int e = 0; e < 8; ++e) {
        const int k = 64 * wv + 32 * kk + 8 * g + e;
        wgdA[m][kk][e] = (__bf16)Wm[k * 16 + s];
      }
    }
  }
  f32x4 bias_h[4];
#pragma unroll
  for (int m = 0; m < 4; ++m)
    bias_h[m] = *(const f32x4*)(b_h + 64 * wv + 16 * m + 4 * g);
  const f32x4 bias_g = *(const f32x4*)(b_g + 4 * g);
  const f32x4 bias_d = *(const f32x4*)(b_d + 4 * g);
  const f32x4 zero4 = {0.0f, 0.0f, 0.0f, 0.0f};

  const int* qrow = questions + (size_t)bs * Sn;
  const int* rrow = responses + (size_t)bs * Sn;

  f32x4 th = *(const f32x4*)(theta_embed +
                             (size_t)student_ids[(size_t)bs * Sn] * 16 + 4 * g);

  int r = rrow[0];
  int q0 = qrow[0];
  float4 a4 = *(const float4*)(alpha_q + (size_t)q0 * 16 + 4 * g);
  float4 bq = beta_q4[q0];
  float4 bsC = bsumC_q4[q0];
  int qn = qrow[1], rn = rrow[1];

#pragma unroll 2
  for (int t = 0; t < Sn; ++t) {
    // prefetch t+1 params + t+2 indices (stay in flight across the lgkm-only barrier)
    const float4 a4n = *(const float4*)(alpha_q + (size_t)qn * 16 + 4 * g);
    const float4 bqn = beta_q4[qn];
    const float4 bsCn = bsumC_q4[qn];
    const int t2 = (t + 2 < Sn) ? t + 2 : Sn - 1;
    const int qn2 = qrow[t2];
    const int rn2 = rrow[t2];

    // ---- Phase A: z, softmax (log2 domain), surprise (replicated per wave) ----
    float zp = a4.x * th.x + a4.y * th.y + a4.z * th.z + a4.w * th.w;
    zp += __shfl_xor(zp, 16);
    zp += __shfl_xor(zp, 32);
    const float z2 = zp * LOG2E;

    // independent scaled logits: lC_k = k*z2 - bsC_k
    const float lc1 = z2 - bsC.x;
    const float lc2 = fmaf(2.0f, z2, -bsC.y);
    const float lc3 = fmaf(3.0f, z2, -bsC.z);
    const float lc4 = fmaf(4.0f, z2, -bsC.w);
    const float m = fmaxf(fmaxf(fmaxf(lc1, lc2), fmaxf(lc3, lc4)), 0.0f);
    const float e0 = fexp2(-m);
    const float e1 = fexp2(lc1 - m);
    const float e2 = fexp2(lc2 - m);
    const float e3 = fexp2(lc3 - m);
    const float e4 = fexp2(lc4 - m);
    const float inv = frcp(e0 + e1 + e2 + e3 + e4);
    const float expected = (e1 + 2.0f * e2 + 3.0f * e3 + 4.0f * e4) * inv;
    const float surprise = (float)r - expected;

    // ---- outputs: distributed across waves (balanced barrier arrival) ----
    const size_t pos = (size_t)bs * Sn + t;
    if (wv == 0) {
      *(f32x4*)(out_theta + pos * 16 + 4 * g) = th;
    } else if (wv == 1) {
      const float lv =
          (g == 0) ? 0.0f : (g == 1) ? lc1 * LN2 : (g == 2) ? lc2 * LN2 : lc3 * LN2;
      out_logits[pos * 5 + g] = lv;
    } else if (wv == 2) {
      const float pv = ((g == 0) ? e0 : (g == 1) ? e1 : (g == 2) ? e2 : e3) * inv;
      out_probs[pos * 5 + g] = pv;
    } else {
      if (g == 3) {
        out_logits[pos * 5 + 4] = lc4 * LN2;
        out_probs[pos * 5 + 4] = e4 * inv;
      }
    }

    // ---- write U^T (own wave's copy), bf16 ----
    {
      char* ur = uB + s * UST;
      u16x4 thb = {f2b(th.x), f2b(th.y), f2b(th.z), f2b(th.w)};
      *(u16x4*)(ur + 8 * g) = thb;
      u16x4 ab = {f2b(a4.x), f2b(a4.y), f2b(a4.z), f2b(a4.w)};
      *(u16x4*)(ur + 32 + 8 * g) = ab;
      if (g == 0) {
        u16x4 sb = {f2b(surprise), f2b(bq.x), f2b(bq.y), f2b(bq.z)};
        *(u16x4*)(ur + 64) = sb;
        *(unsigned short*)(ur + 72) = f2b(bq.w);
      }
    }
    WAVE_FENCE();

    // ---- Phase B: 64-row slice of H^T = Wh^T @ U^T (8 MFMA) ----
    const bf16x8 ub0 = *(const bf16x8*)(uB + s * UST + 16 * g);
    const bf16x8 ub1 = *(const bf16x8*)(uB + s * UST + 64 + 16 * g);
    f32x4 acc0 = __builtin_amdgcn_mfma_f32_16x16x32_bf16(whA[0][0], ub0, bias_h[0], 0, 0, 0);
    f32x4 acc1 = __builtin_amdgcn_mfma_f32_16x16x32_bf16(whA[1][0], ub0, bias_h[1], 0, 0, 0);
    f32x4 acc2 = __builtin_amdgcn_mfma_f32_16x16x32_bf16(whA[2][0], ub0, bias_h[2], 0, 0, 0);
    f32x4 acc3 = __builtin_amdgcn_mfma_f32_16x16x32_bf16(whA[3][0], ub0, bias_h[3], 0, 0, 0);
    acc0 = __builtin_amdgcn_mfma_f32_16x16x32_bf16(whA[0][1], ub1, acc0, 0, 0, 0);
    acc1 = __builtin_amdgcn_mfma_f32_16x16x32_bf16(whA[1][1], ub1, acc1, 0, 0, 0);
    acc2 = __builtin_amdgcn_mfma_f32_16x16x32_bf16(whA[2][1], ub1, acc2, 0, 0, 0);
    acc3 = __builtin_amdgcn_mfma_f32_16x16x32_bf16(whA[3][1], ub1, acc3, 0, 0, 0);

    // tanh + pack -> own 128B chunk of H rows (wave-private)
    {
      char* hr = sH + s * HST + 128 * wv + 8 * g;
      u16x4 h0 = {f2b(ftanh(acc0.x)), f2b(ftanh(acc0.y)), f2b(ftanh(acc0.z)), f2b(ftanh(acc0.w))};
      *(u16x4*)(hr) = h0;
      u16x4 h1 = {f2b(ftanh(acc1.x)), f2b(ftanh(acc1.y)), f2b(ftanh(acc1.z)), f2b(ftanh(acc1.w))};
      *(u16x4*)(hr + 32) = h1;
      u16x4 h2 = {f2b(ftanh(acc2.x)), f2b(ftanh(acc2.y)), f2b(ftanh(acc2.z)), f2b(ftanh(acc2.w))};
      *(u16x4*)(hr + 64) = h2;
      u16x4 h3 = {f2b(ftanh(acc3.x)), f2b(ftanh(acc3.y)), f2b(ftanh(acc3.z)), f2b(ftanh(acc3.w))};
      *(u16x4*)(hr + 96) = h3;
    }
    WAVE_FENCE();  // own-wave H RAW

    // ---- Phase C partial: gate/delta over OWN K-slice (4 MFMA, no barrier) ----
    const char* hr = sH + s * HST + 128 * wv + 16 * g;
    const bf16x8 hb0 = *(const bf16x8*)(hr);
    const bf16x8 hb1 = *(const bf16x8*)(hr + 64);
    f32x4 pg = __builtin_amdgcn_mfma_f32_16x16x32_bf16(wgdA[0][0], hb0, zero4, 0, 0, 0);
    f32x4 pd = __builtin_amdgcn_mfma_f32_16x16x32_bf16(wgdA[1][0], hb0, zero4, 0, 0, 0);
    pg = __builtin_amdgcn_mfma_f32_16x16x32_bf16(wgdA[0][1], hb1, pg, 0, 0, 0);
    pd = __builtin_amdgcn_mfma_f32_16x16x32_bf16(wgdA[1][1], hb1, pd, 0, 0, 0);

    // exchange partials
    char* sPp = sP + (t & 1) * PBUF;
    {
      char* pp = sPp + wv * PWV + lane * PLN;
      *(f32x4*)pp = pg;
      *(f32x4*)(pp + 16) = pd;
    }
    BLOCK_SYNC();  // the one barrier per step (balanced arrival)

    // ---- reduce partials (own in reg + 3 others) + theta update ----
    f32x4 ag = bias_g + pg;
    f32x4 ad = bias_d + pd;
    {
      const char* p1 = sPp + (((wv + 1) & 3) * PWV) + lane * PLN;
      const char* p2 = sPp + (((wv + 2) & 3) * PWV) + lane * PLN;
      const char* p3 = sPp + (((wv + 3) & 3) * PWV) + lane * PLN;
      ag += *(const f32x4*)p1;
      ad += *(const f32x4*)(p1 + 16);
      ag += *(const f32x4*)p2;
      ad += *(const f32x4*)(p2 + 16);
      ag += *(const f32x4*)p3;
      ad += *(const f32x4*)(p3 + 16);
    }
    th.x += fsigmoid(ag.x) * ftanh(ad.x);
    th.y += fsigmoid(ag.y) * ftanh(ad.y);
    th.z += fsigmoid(ag.z) * ftanh(ad.z);
    th.w += fsigmoid(ag.w) * ftanh(ad.w);

    // rotate prefetched state
    a4 = a4n; bq = bqn; bsC = bsCn; r = rn;
    qn = qn2; rn = rn2;
  }
}

}  // namespace

extern "C" void kernel_launch(void* const* d_in, const int* in_sizes, int n_in,
                              void* d_out, int out_size, void* d_ws, size_t ws_size,
                              hipStream_t stream) {
  const float* theta_embed = (const float*)d_in[0];
  const float* alpha_raw   = (const float*)d_in[1];
  const float* beta_base   = (const float*)d_in[2];
  const float* beta_gaps   = (const float*)d_in[3];
  const float* W_h = (const float*)d_in[4];
  const float* b_h = (const float*)d_in[5];
  const float* W_g = (const float*)d_in[6];
  const float* b_g = (const float*)d_in[7];
  const float* W_d = (const float*)d_in[8];
  const float* b_d = (const float*)d_in[9];
  const int* student_ids = (const int*)d_in[10];
  const int* questions   = (const int*)d_in[11];
  const int* responses   = (const int*)d_in[12];

  float* out = (float*)d_out;
  float* out_theta  = out;
  float* out_alpha  = out_theta + (size_t)Bn * Sn * 16;
  float* out_beta   = out_alpha + (size_t)Bn * Sn * 16;
  float* out_logits = out_beta  + (size_t)Bn * Sn * 4;
  float* out_probs  = out_logits + (size_t)Bn * Sn * 5;

  float* alpha_q = (float*)d_ws;                      // (Q+1)*16 floats
  float* beta_q  = alpha_q + (size_t)(Qn + 1) * 16;   // (Q+1)*4 floats
  float* bsumC_q = beta_q + (size_t)(Qn + 1) * 4;     // (Q+1)*4 floats

  hipLaunchKernelGGL(precompute_kernel, dim3(63), dim3(256), 0, stream,
                     alpha_raw, beta_base, beta_gaps, alpha_q, beta_q, bsumC_q);
  hipLaunchKernelGGL(itemout_kernel, dim3((Bn * Sn * 4) / 256), dim3(256), 0, stream,
                     questions, (const float4*)alpha_q, (const float4*)beta_q,
                     (float4*)out_alpha, (float4*)out_beta);
  hipLaunchKernelGGL(scan_kernel, dim3(Bn / 16), dim3(256), 0, stream,
                     theta_embed, W_h, b_h, W_g, b_g, W_d, b_d,
                     student_ids, questions, responses,
                     alpha_q, (const float4*)beta_q, (const float4*)bsumC_q,
                     out_theta, out_logits, out_probs);
}

// Round 9
// 865.961 us; speedup vs baseline: 1.1185x; 1.1185x over previous
//
#include <hip/hip_runtime.h>
#include <cstddef>
#include <cstdint>

// DynamicGPCM: B=4096 sequences, S=512 steps, D=16, K=5, H=256, IN=37.
// Outputs (f32, concat): theta(B,S,16) | alpha(B,S,16) | beta(B,S,4) | logits(B,S,5) | probs(B,S,5)
//
// R9 = R7 phase structure (B: per-wave 64-row MFMA slice; C: replicated 16-MFMA) with:
//  - 2 independent blocks/CU: grid 512, 8 real seqs/block (N-slots 8..15 mirror 0..7),
//    __launch_bounds__(256,2). Un-synchronized blocks fill each other's stall windows.
//  - U restructure: theta/alpha/beta columns written at END of previous step; only the
//    2-byte surprise column is on the softmax critical path. ub0 (theta+alpha) is read
//    at loop-top and its 4 MFMAs issue while softmax computes.
//  - log2-domain logits (independent FMAs feeding v_exp_f32 directly).
//  - distributed output stores (w0 theta, w1 logits, w2 probs, w3 tail).
// U cols = [theta 0-15 | a 16-31 | beta 32-35 | surprise 36]; W_h rows
//        = [theta 0-15 | surprise 16 | a 17-32 | beta 33-36].

namespace {
constexpr int Bn = 4096;
constexpr int Sn = 512;
constexpr int Qn = 1000;

constexpr int UST = 144;    // U row stride (bytes)
constexpr int HST = 528;    // H row stride (bytes)

constexpr float LOG2E = 1.44269504088896f;
constexpr float LN2 = 0.693147180559945f;

typedef __attribute__((ext_vector_type(8))) __bf16 bf16x8;
typedef __attribute__((ext_vector_type(4))) float f32x4;
typedef __attribute__((ext_vector_type(4))) unsigned short u16x4;

__device__ __forceinline__ float frcp(float x) { return __builtin_amdgcn_rcpf(x); }
__device__ __forceinline__ float fexp2(float x) {
  float r;
  asm("v_exp_f32 %0, %1" : "=v"(r) : "v"(x));
  return r;
}
__device__ __forceinline__ float ftanh(float x) {
  return 1.0f - 2.0f * frcp(fexp2(x * 2.88539008177793f) + 1.0f);
}
__device__ __forceinline__ float fsigmoid(float x) {
  return frcp(1.0f + fexp2(x * -LOG2E));
}
__device__ __forceinline__ float fsoftplus(float x) {
  return (x > 20.0f) ? x : log1pf(__expf(x));
}
__device__ __forceinline__ unsigned short f2b(float x) {
  return __builtin_bit_cast(unsigned short, (__bf16)x);
}
// U col -> W_h row: theta 0-15 -> 0-15; a 16-31 -> 17-32; beta 32-35 -> 33-36; surprise 36 -> 16
__device__ __forceinline__ int permk(int k) {
  if (k < 16) return k;
  if (k < 36) return k + 1;
  return 16;
}

#define WAVE_FENCE() asm volatile("s_waitcnt lgkmcnt(0)" ::: "memory")
#define BLOCK_SYNC()                                        \
  do {                                                      \
    asm volatile("s_waitcnt lgkmcnt(0)" ::: "memory");      \
    __builtin_amdgcn_s_barrier();                           \
    asm volatile("" ::: "memory");                          \
  } while (0)

// ---- Kernel A: per-question item parameters ----
__global__ void precompute_kernel(const float* __restrict__ alpha_raw,
                                  const float* __restrict__ beta_base,
                                  const float* __restrict__ beta_gaps,
                                  float* __restrict__ alpha_q,
                                  float* __restrict__ beta_q,
                                  float* __restrict__ bsumC_q) {
  int tid = blockIdx.x * 256 + threadIdx.x;
  if (tid < (Qn + 1) * 16) alpha_q[tid] = __expf(0.3f * alpha_raw[tid]);
  if (tid < Qn + 1) {
    float base = beta_base[tid];
    float sp0 = fsoftplus(beta_gaps[tid * 3 + 0]);
    float sp1 = fsoftplus(beta_gaps[tid * 3 + 1]);
    float sp2 = fsoftplus(beta_gaps[tid * 3 + 2]);
    float b1 = base, b2 = base + sp0, b3 = b2 + sp1, b4 = b3 + sp2;
    beta_q[tid * 4 + 0] = b1;
    beta_q[tid * 4 + 1] = b2;
    beta_q[tid * 4 + 2] = b3;
    beta_q[tid * 4 + 3] = b4;
    float c1 = b1, c2 = c1 + b2, c3 = c2 + b3, c4 = c3 + b4;
    bsumC_q[tid * 4 + 0] = c1 * LOG2E;
    bsumC_q[tid * 4 + 1] = c2 * LOG2E;
    bsumC_q[tid * 4 + 2] = c3 * LOG2E;
    bsumC_q[tid * 4 + 3] = c4 * LOG2E;
  }
}

// ---- Kernel B: gather alpha/beta output tensors ----
__global__ void itemout_kernel(const int* __restrict__ questions,
                               const float4* __restrict__ alpha_q4,
                               const float4* __restrict__ beta_q4,
                               float4* __restrict__ out_alpha4,
                               float4* __restrict__ out_beta4) {
  int tid = blockIdx.x * 256 + threadIdx.x;
  int pos = tid >> 2, j = tid & 3;
  if (pos >= Bn * Sn) return;
  int q = questions[pos];
  out_alpha4[(size_t)pos * 4 + j] = alpha_q4[(size_t)q * 4 + j];
  if (j == 0) out_beta4[pos] = beta_q4[q];
}

// ---- Kernel C: MFMA scan. 256 threads (4 waves), 8 real seqs, grid 512 ----
__global__ __launch_bounds__(256, 2) void scan_kernel(
    const float* __restrict__ theta_embed,
    const float* __restrict__ W_h, const float* __restrict__ b_h,
    const float* __restrict__ W_g, const float* __restrict__ b_g,
    const float* __restrict__ W_d, const float* __restrict__ b_d,
    const int* __restrict__ student_ids, const int* __restrict__ questions,
    const int* __restrict__ responses,
    const float* __restrict__ alpha_q, const float4* __restrict__ beta_q4,
    const float4* __restrict__ bsumC_q4,
    float* __restrict__ out_theta, float* __restrict__ out_logits,
    float* __restrict__ out_probs) {
  __shared__ char sU[4 * 16 * UST];   // per-wave U^T: [16 s][64 k] bf16
  __shared__ char sH[2 * 16 * HST];   // H: [16 s][256 j] bf16, dbuf

  const int tid = threadIdx.x;
  const int lane = tid & 63;
  const int wv = tid >> 6;        // 0..3
  const int s = lane & 15;        // N-slot; slots 8..15 mirror 0..7
  const int g = lane >> 4;        // quad group
  const int bs = blockIdx.x * 8 + (s & 7);
  const bool real = (lane & 8) == 0;  // s < 8

  char* uB = sU + wv * (16 * UST);
  {  // zero the used 128B of each U row (pad cols 37..63 stay 0 forever)
    int4 zz = {0, 0, 0, 0};
    char* p = uB + (lane >> 2) * UST + (lane & 3) * 32;
    *(int4*)p = zz;
    *(int4*)(p + 16) = zz;
  }

  // ---- A-fragments: Wh^T slice for this wave's 64 j-rows ----
  bf16x8 whA[4][2];
#pragma unroll
  for (int m = 0; m < 4; ++m) {
    const int j = 64 * wv + 16 * m + s;
#pragma unroll
    for (int kk = 0; kk < 2; ++kk) {
#pragma unroll
      for (int e = 0; e < 8; ++e) {
        const int k = kk * 32 + g * 8 + e;
        float v = 0.0f;
        if (k < 37) v = W_h[permk(k) * 256 + j];
        whA[m][kk][e] = (__bf16)v;
      }
    }
  }
  // ---- A-fragments: [Wg^T ; Wd^T], full K=256, replicated per wave ----
  bf16x8 wgdA[2][8];
#pragma unroll
  for (int m = 0; m < 2; ++m) {
    const float* Wm = m ? W_d : W_g;
#pragma unroll
    for (int kk = 0; kk < 8; ++kk) {
#pragma unroll
      for (int e = 0; e < 8; ++e) {
        const int k = kk * 32 + g * 8 + e;
        wgdA[m][kk][e] = (__bf16)Wm[k * 16 + s];
      }
    }
  }
  f32x4 bias_h[4];
#pragma unroll
  for (int m = 0; m < 4; ++m)
    bias_h[m] = *(const f32x4*)(b_h + 64 * wv + 16 * m + 4 * g);
  const f32x4 bias_g = *(const f32x4*)(b_g + 4 * g);
  const f32x4 bias_d = *(const f32x4*)(b_d + 4 * g);
  const f32x4 zero4 = {0.0f, 0.0f, 0.0f, 0.0f};

  const int* qrow = questions + (size_t)bs * Sn;
  const int* rrow = responses + (size_t)bs * Sn;

  f32x4 th = *(const f32x4*)(theta_embed +
                             (size_t)student_ids[(size_t)bs * Sn] * 16 + 4 * g);

  int r = rrow[0];
  int q0 = qrow[0];
  float4 a4 = *(const float4*)(alpha_q + (size_t)q0 * 16 + 4 * g);
  float4 bq = beta_q4[q0];
  float4 bsC = bsumC_q4[q0];
  int qn = qrow[1], rn = rrow[1];

  // ---- preamble: write t=0's theta/alpha/beta U columns ----
  {
    char* ur = uB + s * UST;
    u16x4 thb = {f2b(th.x), f2b(th.y), f2b(th.z), f2b(th.w)};
    *(u16x4*)(ur + 8 * g) = thb;
    u16x4 ab = {f2b(a4.x), f2b(a4.y), f2b(a4.z), f2b(a4.w)};
    *(u16x4*)(ur + 32 + 8 * g) = ab;
    if (g == 0) {
      u16x4 bb = {f2b(bq.x), f2b(bq.y), f2b(bq.z), f2b(bq.w)};
      *(u16x4*)(ur + 64) = bb;   // beta cols 32-35
    }
  }

  for (int t = 0; t < Sn; ++t) {
    // U's theta/alpha/beta cols for step t were written at end of t-1 (or preamble).
    WAVE_FENCE();
    const bf16x8 ub0 = *(const bf16x8*)(uB + s * UST + 16 * g);  // cols 0-31 slice

    // prefetch t+1 params + t+2 indices
    const float4 a4n = *(const float4*)(alpha_q + (size_t)qn * 16 + 4 * g);
    const float4 bqn = beta_q4[qn];
    const float4 bsCn = bsumC_q4[qn];
    const int t2 = (t + 2 < Sn) ? t + 2 : Sn - 1;
    const int qn2 = qrow[t2];
    const int rn2 = rrow[t2];

    // ---- Phase A: z, softmax (log2 domain), surprise ----
    float zp = a4.x * th.x + a4.y * th.y + a4.z * th.z + a4.w * th.w;
    zp += __shfl_xor(zp, 16);
    zp += __shfl_xor(zp, 32);
    const float z2 = zp * LOG2E;

    const float lc1 = z2 - bsC.x;
    const float lc2 = fmaf(2.0f, z2, -bsC.y);
    const float lc3 = fmaf(3.0f, z2, -bsC.z);
    const float lc4 = fmaf(4.0f, z2, -bsC.w);
    const float m = fmaxf(fmaxf(fmaxf(lc1, lc2), fmaxf(lc3, lc4)), 0.0f);
    const float e0 = fexp2(-m);
    const float e1 = fexp2(lc1 - m);
    const float e2 = fexp2(lc2 - m);
    const float e3 = fexp2(lc3 - m);
    const float e4 = fexp2(lc4 - m);
    const float inv = frcp(e0 + e1 + e2 + e3 + e4);
    const float expected = (e1 + 2.0f * e2 + 3.0f * e3 + 4.0f * e4) * inv;
    const float surprise = (float)r - expected;

    // ---- Phase B part 1: 4 MFMA on ub0 (independent of surprise) ----
    f32x4 acc0 = __builtin_amdgcn_mfma_f32_16x16x32_bf16(whA[0][0], ub0, bias_h[0], 0, 0, 0);
    f32x4 acc1 = __builtin_amdgcn_mfma_f32_16x16x32_bf16(whA[1][0], ub0, bias_h[1], 0, 0, 0);
    f32x4 acc2 = __builtin_amdgcn_mfma_f32_16x16x32_bf16(whA[2][0], ub0, bias_h[2], 0, 0, 0);
    f32x4 acc3 = __builtin_amdgcn_mfma_f32_16x16x32_bf16(whA[3][0], ub0, bias_h[3], 0, 0, 0);

    // surprise col 36 (the only U write on the softmax chain)
    if (g == 0) *(unsigned short*)(uB + s * UST + 72) = f2b(surprise);

    // ---- outputs: distributed across waves (off the critical chain) ----
    const size_t pos = (size_t)bs * Sn + t;
    if (wv == 0) {
      if (real) *(f32x4*)(out_theta + pos * 16 + 4 * g) = th;
    } else if (wv == 1) {
      if (real) {
        const float lv =
            (g == 0) ? 0.0f : (g == 1) ? lc1 * LN2 : (g == 2) ? lc2 * LN2 : lc3 * LN2;
        out_logits[pos * 5 + g] = lv;
      }
    } else if (wv == 2) {
      if (real) {
        const float pv = ((g == 0) ? e0 : (g == 1) ? e1 : (g == 2) ? e2 : e3) * inv;
        out_probs[pos * 5 + g] = pv;
      }
    } else {
      if (real && g == 3) {
        out_logits[pos * 5 + 4] = lc4 * LN2;
        out_probs[pos * 5 + 4] = e4 * inv;
      }
    }

    WAVE_FENCE();
    const bf16x8 ub1 = *(const bf16x8*)(uB + s * UST + 64 + 16 * g);  // cols 32-63 slice

    // ---- Phase B part 2 ----
    acc0 = __builtin_amdgcn_mfma_f32_16x16x32_bf16(whA[0][1], ub1, acc0, 0, 0, 0);
    acc1 = __builtin_amdgcn_mfma_f32_16x16x32_bf16(whA[1][1], ub1, acc1, 0, 0, 0);
    acc2 = __builtin_amdgcn_mfma_f32_16x16x32_bf16(whA[2][1], ub1, acc2, 0, 0, 0);
    acc3 = __builtin_amdgcn_mfma_f32_16x16x32_bf16(whA[3][1], ub1, acc3, 0, 0, 0);

    // tanh + pack -> H[s][j] bf16 (lane holds j = 64wv+16m+4g+r)
    char* hB = sH + (t & 1) * (16 * HST);
    {
      char* hr = hB + s * HST + 128 * wv + 8 * g;
      u16x4 h0 = {f2b(ftanh(acc0.x)), f2b(ftanh(acc0.y)), f2b(ftanh(acc0.z)), f2b(ftanh(acc0.w))};
      *(u16x4*)(hr) = h0;
      u16x4 h1 = {f2b(ftanh(acc1.x)), f2b(ftanh(acc1.y)), f2b(ftanh(acc1.z)), f2b(ftanh(acc1.w))};
      *(u16x4*)(hr + 32) = h1;
      u16x4 h2 = {f2b(ftanh(acc2.x)), f2b(ftanh(acc2.y)), f2b(ftanh(acc2.z)), f2b(ftanh(acc2.w))};
      *(u16x4*)(hr + 64) = h2;
      u16x4 h3 = {f2b(ftanh(acc3.x)), f2b(ftanh(acc3.y)), f2b(ftanh(acc3.z)), f2b(ftanh(acc3.w))};
      *(u16x4*)(hr + 96) = h3;
    }
    BLOCK_SYNC();  // the one barrier per step (H is double-buffered)

    // ---- Phase C: [gate;delta]^T = Wgd^T @ H^T, 4 parallel 4-deep chains ----
    const char* hr = hB + s * HST + 16 * g;
    f32x4 ag0 = bias_g, ad0 = bias_d, ag1 = zero4, ad1 = zero4;
#pragma unroll
    for (int kk = 0; kk < 4; ++kk) {
      const bf16x8 hb = *(const bf16x8*)(hr + 64 * kk);
      ag0 = __builtin_amdgcn_mfma_f32_16x16x32_bf16(wgdA[0][kk], hb, ag0, 0, 0, 0);
      ad0 = __builtin_amdgcn_mfma_f32_16x16x32_bf16(wgdA[1][kk], hb, ad0, 0, 0, 0);
    }
#pragma unroll
    for (int kk = 4; kk < 8; ++kk) {
      const bf16x8 hb = *(const bf16x8*)(hr + 64 * kk);
      ag1 = __builtin_amdgcn_mfma_f32_16x16x32_bf16(wgdA[0][kk], hb, ag1, 0, 0, 0);
      ad1 = __builtin_amdgcn_mfma_f32_16x16x32_bf16(wgdA[1][kk], hb, ad1, 0, 0, 0);
    }
    const f32x4 ag = ag0 + ag1;
    const f32x4 ad = ad0 + ad1;
    th.x += fsigmoid(ag.x) * ftanh(ad.x);
    th.y += fsigmoid(ag.y) * ftanh(ad.y);
    th.z += fsigmoid(ag.z) * ftanh(ad.z);
    th.w += fsigmoid(ag.w) * ftanh(ad.w);

    // ---- write t+1's theta/alpha/beta U columns (off next step's chain) ----
    {
      char* ur = uB + s * UST;
      u16x4 thb = {f2b(th.x), f2b(th.y), f2b(th.z), f2b(th.w)};
      *(u16x4*)(ur + 8 * g) = thb;
      u16x4 ab = {f2b(a4n.x), f2b(a4n.y), f2b(a4n.z), f2b(a4n.w)};
      *(u16x4*)(ur + 32 + 8 * g) = ab;
      if (g == 0) {
        u16x4 bb = {f2b(bqn.x), f2b(bqn.y), f2b(bqn.z), f2b(bqn.w)};
        *(u16x4*)(ur + 64) = bb;
      }
    }

    // rotate prefetched state
    a4 = a4n; bq = bqn; bsC = bsCn; r = rn;
    qn = qn2; rn = rn2;
  }
  (void)bq;
}

}  // namespace

extern "C" void kernel_launch(void* const* d_in, const int* in_sizes, int n_in,
                              void* d_out, int out_size, void* d_ws, size_t ws_size,
                              hipStream_t stream) {
  const float* theta_embed = (const float*)d_in[0];
  const float* alpha_raw   = (const float*)d_in[1];
  const float* beta_base   = (const float*)d_in[2];
  const float* beta_gaps   = (const float*)d_in[3];
  const float* W_h = (const float*)d_in[4];
  const float* b_h = (const float*)d_in[5];
  const float* W_g = (const float*)d_in[6];
  const float* b_g = (const float*)d_in[7];
  const float* W_d = (const float*)d_in[8];
  const float* b_d = (const float*)d_in[9];
  const int* student_ids = (const int*)d_in[10];
  const int* questions   = (const int*)d_in[11];
  const int* responses   = (const int*)d_in[12];

  float* out = (float*)d_out;
  float* out_theta  = out;
  float* out_alpha  = out_theta + (size_t)Bn * Sn * 16;
  float* out_beta   = out_alpha + (size_t)Bn * Sn * 16;
  float* out_logits = out_beta  + (size_t)Bn * Sn * 4;
  float* out_probs  = out_logits + (size_t)Bn * Sn * 5;

  float* alpha_q = (float*)d_ws;                      // (Q+1)*16 floats
  float* beta_q  = alpha_q + (size_t)(Qn + 1) * 16;   // (Q+1)*4 floats
  float* bsumC_q = beta_q + (size_t)(Qn + 1) * 4;     // (Q+1)*4 floats

  hipLaunchKernelGGL(precompute_kernel, dim3(63), dim3(256), 0, stream,
                     alpha_raw, beta_base, beta_gaps, alpha_q, beta_q, bsumC_q);
  hipLaunchKernelGGL(itemout_kernel, dim3((Bn * Sn * 4) / 256), dim3(256), 0, stream,
                     questions, (const float4*)alpha_q, (const float4*)beta_q,
                     (float4*)out_alpha, (float4*)out_beta);
  hipLaunchKernelGGL(scan_kernel, dim3(Bn / 8), dim3(256), 0, stream,
                     theta_embed, W_h, b_h, W_g, b_g, W_d, b_d,
                     student_ids, questions, responses,
                     alpha_q, (const float4*)beta_q, (const float4*)bsumC_q,
                     out_theta, out_logits, out_probs);
}

// Round 10
// 832.768 us; speedup vs baseline: 1.1631x; 1.0399x over previous
//
#include <hip/hip_runtime.h>
#include <cstddef>
#include <cstdint>

// DynamicGPCM: B=4096 sequences, S=512 steps, D=16, K=5, H=256, IN=37.
// Outputs (f32, concat): theta(B,S,16) | alpha(B,S,16) | beta(B,S,4) | logits(B,S,5) | probs(B,S,5)
//
// R10 = R7 per-group structure, TWO independent 16-seq groups per block:
//   grid 128, 8 waves; waves 0-3 = group 0, waves 4-7 = group 1. Each SIMD hosts
//   one wave of each group -> two independent serial chains interleave, filling
//   the ~1900 cyc/step dependency stall R7 exposed at 1 wave/SIMD. Per-seq issue
//   cost unchanged (R9's mirror-slot mistake avoided). Groups share only the
//   block barrier (same cadence). Carried from R8/R9: log2-domain logits
//   (independent FMAs -> v_exp_f32), distributed output stores.

namespace {
constexpr int Bn = 4096;
constexpr int Sn = 512;
constexpr int Qn = 1000;

constexpr int UST = 144;    // U row stride (bytes)
constexpr int HST = 528;    // H row stride (bytes)
constexpr int UGRP = 16 * UST;      // 2304 B per wave's U copy
constexpr int HGRP = 16 * HST;      // 8448 B per H buffer

constexpr float LOG2E = 1.44269504088896f;
constexpr float LN2 = 0.693147180559945f;

typedef __attribute__((ext_vector_type(8))) __bf16 bf16x8;
typedef __attribute__((ext_vector_type(4))) float f32x4;
typedef __attribute__((ext_vector_type(4))) unsigned short u16x4;

__device__ __forceinline__ float frcp(float x) { return __builtin_amdgcn_rcpf(x); }
__device__ __forceinline__ float fexp2(float x) {
  float r;
  asm("v_exp_f32 %0, %1" : "=v"(r) : "v"(x));
  return r;
}
__device__ __forceinline__ float ftanh(float x) {
  return 1.0f - 2.0f * frcp(fexp2(x * 2.88539008177793f) + 1.0f);
}
__device__ __forceinline__ float fsigmoid(float x) {
  return frcp(1.0f + fexp2(x * -LOG2E));
}
__device__ __forceinline__ float fsoftplus(float x) {
  return (x > 20.0f) ? x : log1pf(__expf(x));
}
__device__ __forceinline__ unsigned short f2b(float x) {
  return __builtin_bit_cast(unsigned short, (__bf16)x);
}
// u-column permutation: U cols = [theta 0-15 | a 16-31 | surprise 32 | beta 33-36]
// W_h rows  = [theta 0-15 | surprise 16 | a 17-32 | beta 33-36]
__device__ __forceinline__ int permk(int k) {
  if (k < 16) return k;
  if (k < 32) return k + 1;
  if (k == 32) return 16;
  return k;
}

#define WAVE_FENCE() asm volatile("s_waitcnt lgkmcnt(0)" ::: "memory")
#define BLOCK_SYNC()                                        \
  do {                                                      \
    asm volatile("s_waitcnt lgkmcnt(0)" ::: "memory");      \
    __builtin_amdgcn_s_barrier();                           \
    asm volatile("" ::: "memory");                          \
  } while (0)

// ---- Kernel A: per-question item parameters ----
__global__ void precompute_kernel(const float* __restrict__ alpha_raw,
                                  const float* __restrict__ beta_base,
                                  const float* __restrict__ beta_gaps,
                                  float* __restrict__ alpha_q,
                                  float* __restrict__ beta_q,
                                  float* __restrict__ bsumC_q) {
  int tid = blockIdx.x * 256 + threadIdx.x;
  if (tid < (Qn + 1) * 16) alpha_q[tid] = __expf(0.3f * alpha_raw[tid]);
  if (tid < Qn + 1) {
    float base = beta_base[tid];
    float sp0 = fsoftplus(beta_gaps[tid * 3 + 0]);
    float sp1 = fsoftplus(beta_gaps[tid * 3 + 1]);
    float sp2 = fsoftplus(beta_gaps[tid * 3 + 2]);
    float b1 = base, b2 = base + sp0, b3 = b2 + sp1, b4 = b3 + sp2;
    beta_q[tid * 4 + 0] = b1;
    beta_q[tid * 4 + 1] = b2;
    beta_q[tid * 4 + 2] = b3;
    beta_q[tid * 4 + 3] = b4;
    // cumulative-of-cumulative, scaled by log2(e): lC_k = k*z*log2e - bsC_k
    float c1 = b1, c2 = c1 + b2, c3 = c2 + b3, c4 = c3 + b4;
    bsumC_q[tid * 4 + 0] = c1 * LOG2E;
    bsumC_q[tid * 4 + 1] = c2 * LOG2E;
    bsumC_q[tid * 4 + 2] = c3 * LOG2E;
    bsumC_q[tid * 4 + 3] = c4 * LOG2E;
  }
}

// ---- Kernel B: gather alpha/beta output tensors ----
__global__ void itemout_kernel(const int* __restrict__ questions,
                               const float4* __restrict__ alpha_q4,
                               const float4* __restrict__ beta_q4,
                               float4* __restrict__ out_alpha4,
                               float4* __restrict__ out_beta4) {
  int tid = blockIdx.x * 256 + threadIdx.x;
  int pos = tid >> 2, j = tid & 3;
  if (pos >= Bn * Sn) return;
  int q = questions[pos];
  out_alpha4[(size_t)pos * 4 + j] = alpha_q4[(size_t)q * 4 + j];
  if (j == 0) out_beta4[pos] = beta_q4[q];
}

// ---- Kernel C: MFMA scan. 512 threads (8 waves = 2 groups x 4), grid 128 ----
__global__ __launch_bounds__(512, 2) void scan_kernel(
    const float* __restrict__ theta_embed,
    const float* __restrict__ W_h, const float* __restrict__ b_h,
    const float* __restrict__ W_g, const float* __restrict__ b_g,
    const float* __restrict__ W_d, const float* __restrict__ b_d,
    const int* __restrict__ student_ids, const int* __restrict__ questions,
    const int* __restrict__ responses,
    const float* __restrict__ alpha_q, const float4* __restrict__ beta_q4,
    const float4* __restrict__ bsumC_q4,
    float* __restrict__ out_theta, float* __restrict__ out_logits,
    float* __restrict__ out_probs) {
  __shared__ char sU[2 * 4 * UGRP];   // [group][wave] U^T: [16 s][64 k] bf16
  __shared__ char sH[2 * 2 * HGRP];   // [group][dbuf] H: [16 s][256 j] bf16

  const int tid = threadIdx.x;
  const int lane = tid & 63;
  const int wv8 = tid >> 6;       // 0..7
  const int gr = wv8 >> 2;        // group 0/1
  const int wv = wv8 & 3;         // wave within group
  const int s = lane & 15;        // seq slot / MFMA N-col (ALL REAL)
  const int g = lane >> 4;        // quad group
  const int bs = blockIdx.x * 32 + gr * 16 + s;

  char* uB = sU + (gr * 4 + wv) * UGRP;
  char* hG = sH + gr * (2 * HGRP);
  {  // zero the used 128B of each U row (pad cols 37..63 stay 0 forever)
    int4 zz = {0, 0, 0, 0};
    char* p = uB + (lane >> 2) * UST + (lane & 3) * 32;
    *(int4*)p = zz;
    *(int4*)(p + 16) = zz;
  }

  // ---- A-fragments: Wh^T slice for this wave's 64 j-rows ----
  bf16x8 whA[4][2];
#pragma unroll
  for (int m = 0; m < 4; ++m) {
    const int j = 64 * wv + 16 * m + s;
#pragma unroll
    for (int kk = 0; kk < 2; ++kk) {
#pragma unroll
      for (int e = 0; e < 8; ++e) {
        const int k = kk * 32 + g * 8 + e;
        float v = 0.0f;
        if (k < 37) v = W_h[permk(k) * 256 + j];
        whA[m][kk][e] = (__bf16)v;
      }
    }
  }
  // ---- A-fragments: [Wg^T ; Wd^T], full K=256, replicated per wave ----
  bf16x8 wgdA[2][8];
#pragma unroll
  for (int m = 0; m < 2; ++m) {
    const float* Wm = m ? W_d : W_g;
#pragma unroll
    for (int kk = 0; kk < 8; ++kk) {
#pragma unroll
      for (int e = 0; e < 8; ++e) {
        const int k = kk * 32 + g * 8 + e;
        wgdA[m][kk][e] = (__bf16)Wm[k * 16 + s];
      }
    }
  }
  f32x4 bias_h[4];
#pragma unroll
  for (int m = 0; m < 4; ++m)
    bias_h[m] = *(const f32x4*)(b_h + 64 * wv + 16 * m + 4 * g);
  const f32x4 bias_g = *(const f32x4*)(b_g + 4 * g);
  const f32x4 bias_d = *(const f32x4*)(b_d + 4 * g);
  const f32x4 zero4 = {0.0f, 0.0f, 0.0f, 0.0f};

  const int* qrow = questions + (size_t)bs * Sn;
  const int* rrow = responses + (size_t)bs * Sn;

  // theta state: th[r] = theta[s][4g+r] (matches Phase-C D layout)
  f32x4 th = *(const f32x4*)(theta_embed +
                             (size_t)student_ids[(size_t)bs * Sn] * 16 + 4 * g);

  int r = rrow[0];
  int q0 = qrow[0];
  float4 a4 = *(const float4*)(alpha_q + (size_t)q0 * 16 + 4 * g);
  float4 bq = beta_q4[q0];
  float4 bsC = bsumC_q4[q0];
  int qn = qrow[1], rn = rrow[1];

#pragma unroll 2
  for (int t = 0; t < Sn; ++t) {
    // prefetch t+1 params + t+2 indices (stay in flight across the lgkm-only barrier)
    const float4 a4n = *(const float4*)(alpha_q + (size_t)qn * 16 + 4 * g);
    const float4 bqn = beta_q4[qn];
    const float4 bsCn = bsumC_q4[qn];
    const int t2 = (t + 2 < Sn) ? t + 2 : Sn - 1;
    const int qn2 = qrow[t2];
    const int rn2 = rrow[t2];

    // ---- Phase A: z, softmax (log2 domain), surprise (replicated per wave) ----
    float zp = a4.x * th.x + a4.y * th.y + a4.z * th.z + a4.w * th.w;
    zp += __shfl_xor(zp, 16);
    zp += __shfl_xor(zp, 32);
    const float z2 = zp * LOG2E;

    // independent scaled logits: lC_k = k*z2 - bsC_k
    const float lc1 = z2 - bsC.x;
    const float lc2 = fmaf(2.0f, z2, -bsC.y);
    const float lc3 = fmaf(3.0f, z2, -bsC.z);
    const float lc4 = fmaf(4.0f, z2, -bsC.w);
    const float m = fmaxf(fmaxf(fmaxf(lc1, lc2), fmaxf(lc3, lc4)), 0.0f);
    const float e0 = fexp2(-m);
    const float e1 = fexp2(lc1 - m);
    const float e2 = fexp2(lc2 - m);
    const float e3 = fexp2(lc3 - m);
    const float e4 = fexp2(lc4 - m);
    const float inv = frcp(e0 + e1 + e2 + e3 + e4);
    const float expected = (e1 + 2.0f * e2 + 3.0f * e3 + 4.0f * e4) * inv;
    const float surprise = (float)r - expected;

    // ---- outputs: distributed across the group's waves (balanced arrival) ----
    const size_t pos = (size_t)bs * Sn + t;
    if (wv == 0) {
      *(f32x4*)(out_theta + pos * 16 + 4 * g) = th;
    } else if (wv == 1) {
      const float lv =
          (g == 0) ? 0.0f : (g == 1) ? lc1 * LN2 : (g == 2) ? lc2 * LN2 : lc3 * LN2;
      out_logits[pos * 5 + g] = lv;
    } else if (wv == 2) {
      const float pv = ((g == 0) ? e0 : (g == 1) ? e1 : (g == 2) ? e2 : e3) * inv;
      out_probs[pos * 5 + g] = pv;
    } else {
      if (g == 3) {
        out_logits[pos * 5 + 4] = lc4 * LN2;
        out_probs[pos * 5 + 4] = e4 * inv;
      }
    }

    // ---- write U^T (own wave's copy), bf16 ----
    {
      char* ur = uB + s * UST;
      u16x4 thb = {f2b(th.x), f2b(th.y), f2b(th.z), f2b(th.w)};
      *(u16x4*)(ur + 8 * g) = thb;                       // theta cols 0-15
      u16x4 ab = {f2b(a4.x), f2b(a4.y), f2b(a4.z), f2b(a4.w)};
      *(u16x4*)(ur + 32 + 8 * g) = ab;                   // a cols 16-31
      if (g == 0) {
        u16x4 sb = {f2b(surprise), f2b(bq.x), f2b(bq.y), f2b(bq.z)};
        *(u16x4*)(ur + 64) = sb;                         // cols 32-35
        *(unsigned short*)(ur + 72) = f2b(bq.w);         // col 36
      }
    }
    WAVE_FENCE();

    // ---- Phase B: 64-row slice of H^T = Wh^T @ U^T (8 MFMA, 4 parallel accs) ----
    const bf16x8 ub0 = *(const bf16x8*)(uB + s * UST + 16 * g);
    const bf16x8 ub1 = *(const bf16x8*)(uB + s * UST + 64 + 16 * g);
    f32x4 acc0 = __builtin_amdgcn_mfma_f32_16x16x32_bf16(whA[0][0], ub0, bias_h[0], 0, 0, 0);
    f32x4 acc1 = __builtin_amdgcn_mfma_f32_16x16x32_bf16(whA[1][0], ub0, bias_h[1], 0, 0, 0);
    f32x4 acc2 = __builtin_amdgcn_mfma_f32_16x16x32_bf16(whA[2][0], ub0, bias_h[2], 0, 0, 0);
    f32x4 acc3 = __builtin_amdgcn_mfma_f32_16x16x32_bf16(whA[3][0], ub0, bias_h[3], 0, 0, 0);
    acc0 = __builtin_amdgcn_mfma_f32_16x16x32_bf16(whA[0][1], ub1, acc0, 0, 0, 0);
    acc1 = __builtin_amdgcn_mfma_f32_16x16x32_bf16(whA[1][1], ub1, acc1, 0, 0, 0);
    acc2 = __builtin_amdgcn_mfma_f32_16x16x32_bf16(whA[2][1], ub1, acc2, 0, 0, 0);
    acc3 = __builtin_amdgcn_mfma_f32_16x16x32_bf16(whA[3][1], ub1, acc3, 0, 0, 0);

    // tanh + pack -> H[s][j] bf16 (lane holds j = 64wv+16m+4g+r, r=0..3)
    char* hB = hG + (t & 1) * HGRP;
    {
      char* hr = hB + s * HST + 128 * wv + 8 * g;
      u16x4 h0 = {f2b(ftanh(acc0.x)), f2b(ftanh(acc0.y)), f2b(ftanh(acc0.z)), f2b(ftanh(acc0.w))};
      *(u16x4*)(hr) = h0;
      u16x4 h1 = {f2b(ftanh(acc1.x)), f2b(ftanh(acc1.y)), f2b(ftanh(acc1.z)), f2b(ftanh(acc1.w))};
      *(u16x4*)(hr + 32) = h1;
      u16x4 h2 = {f2b(ftanh(acc2.x)), f2b(ftanh(acc2.y)), f2b(ftanh(acc2.z)), f2b(ftanh(acc2.w))};
      *(u16x4*)(hr + 64) = h2;
      u16x4 h3 = {f2b(ftanh(acc3.x)), f2b(ftanh(acc3.y)), f2b(ftanh(acc3.z)), f2b(ftanh(acc3.w))};
      *(u16x4*)(hr + 96) = h3;
    }
    BLOCK_SYNC();  // the one barrier per step (H double-buffered; both groups same cadence)

    // ---- Phase C: [gate;delta]^T = Wgd^T @ H^T, 4 parallel 4-deep chains ----
    const char* hr = hB + s * HST + 16 * g;
    f32x4 ag0 = bias_g, ad0 = bias_d, ag1 = zero4, ad1 = zero4;
#pragma unroll
    for (int kk = 0; kk < 4; ++kk) {
      const bf16x8 hb = *(const bf16x8*)(hr + 64 * kk);
      ag0 = __builtin_amdgcn_mfma_f32_16x16x32_bf16(wgdA[0][kk], hb, ag0, 0, 0, 0);
      ad0 = __builtin_amdgcn_mfma_f32_16x16x32_bf16(wgdA[1][kk], hb, ad0, 0, 0, 0);
    }
#pragma unroll
    for (int kk = 4; kk < 8; ++kk) {
      const bf16x8 hb = *(const bf16x8*)(hr + 64 * kk);
      ag1 = __builtin_amdgcn_mfma_f32_16x16x32_bf16(wgdA[0][kk], hb, ag1, 0, 0, 0);
      ad1 = __builtin_amdgcn_mfma_f32_16x16x32_bf16(wgdA[1][kk], hb, ad1, 0, 0, 0);
    }
    const f32x4 ag = ag0 + ag1;
    const f32x4 ad = ad0 + ad1;
    // D layout == theta ownership: update in-register, no exchange
    th.x += fsigmoid(ag.x) * ftanh(ad.x);
    th.y += fsigmoid(ag.y) * ftanh(ad.y);
    th.z += fsigmoid(ag.z) * ftanh(ad.z);
    th.w += fsigmoid(ag.w) * ftanh(ad.w);

    // rotate prefetched state
    a4 = a4n; bq = bqn; bsC = bsCn; r = rn;
    qn = qn2; rn = rn2;
  }
}

}  // namespace

extern "C" void kernel_launch(void* const* d_in, const int* in_sizes, int n_in,
                              void* d_out, int out_size, void* d_ws, size_t ws_size,
                              hipStream_t stream) {
  const float* theta_embed = (const float*)d_in[0];
  const float* alpha_raw   = (const float*)d_in[1];
  const float* beta_base   = (const float*)d_in[2];
  const float* beta_gaps   = (const float*)d_in[3];
  const float* W_h = (const float*)d_in[4];
  const float* b_h = (const float*)d_in[5];
  const float* W_g = (const float*)d_in[6];
  const float* b_g = (const float*)d_in[7];
  const float* W_d = (const float*)d_in[8];
  const float* b_d = (const float*)d_in[9];
  const int* student_ids = (const int*)d_in[10];
  const int* questions   = (const int*)d_in[11];
  const int* responses   = (const int*)d_in[12];

  float* out = (float*)d_out;
  float* out_theta  = out;
  float* out_alpha  = out_theta + (size_t)Bn * Sn * 16;
  float* out_beta   = out_alpha + (size_t)Bn * Sn * 16;
  float* out_logits = out_beta  + (size_t)Bn * Sn * 4;
  float* out_probs  = out_logits + (size_t)Bn * Sn * 5;

  float* alpha_q = (float*)d_ws;                      // (Q+1)*16 floats
  float* beta_q  = alpha_q + (size_t)(Qn + 1) * 16;   // (Q+1)*4 floats
  float* bsumC_q = beta_q + (size_t)(Qn + 1) * 4;     // (Q+1)*4 floats

  hipLaunchKernelGGL(precompute_kernel, dim3(63), dim3(256), 0, stream,
                     alpha_raw, beta_base, beta_gaps, alpha_q, beta_q, bsumC_q);
  hipLaunchKernelGGL(itemout_kernel, dim3((Bn * Sn * 4) / 256), dim3(256), 0, stream,
                     questions, (const float4*)alpha_q, (const float4*)beta_q,
                     (float4*)out_alpha, (float4*)out_beta);
  hipLaunchKernelGGL(scan_kernel, dim3(Bn / 32), dim3(512), 0, stream,
                     theta_embed, W_h, b_h, W_g, b_g, W_d, b_d,
                     student_ids, questions, responses,
                     alpha_q, (const float4*)beta_q, (const float4*)bsumC_q,
                     out_theta, out_logits, out_probs);
}

// Round 11
// 702.346 us; speedup vs baseline: 1.3791x; 1.1857x over previous
//
#include <hip/hip_runtime.h>
#include <cstddef>
#include <cstdint>

// DynamicGPCM: B=4096 sequences, S=512 steps, D=16, K=5, H=256, IN=37.
// Outputs (f32, concat): theta(B,S,16) | alpha(B,S,16) | beta(B,S,4) | logits(B,S,5) | probs(B,S,5)
//
// R11 = R7 config (4 waves x 16 real seqs, grid 256, 1 wave/SIMD) + serial-chain
// shortening (R10 proved 2-chains/SIMD can't fill the chip: 1024 wave-slots exactly):
//  - z(t+1) + its 2 shfl_xor computed at END of step t (overlaps U-writes/fence).
//  - U theta/alpha/beta cols written end-of-prev-step; only surprise on the chain;
//    ub0's 4 MFMAs issue during softmax.
//  - log2-domain logits (independent FMAs -> v_exp_f32).  - distributed stores.
//  - Phase C: 8 parallel 2-deep MFMA chains.
// U cols = [theta 0-15 | a 16-31 | beta 32-35 | surprise 36].

namespace {
constexpr int Bn = 4096;
constexpr int Sn = 512;
constexpr int Qn = 1000;

constexpr int UST = 144;    // U row stride (bytes)
constexpr int HST = 528;    // H row stride (bytes)

constexpr float LOG2E = 1.44269504088896f;
constexpr float LN2 = 0.693147180559945f;

typedef __attribute__((ext_vector_type(8))) __bf16 bf16x8;
typedef __attribute__((ext_vector_type(4))) float f32x4;
typedef __attribute__((ext_vector_type(4))) unsigned short u16x4;

__device__ __forceinline__ float frcp(float x) { return __builtin_amdgcn_rcpf(x); }
__device__ __forceinline__ float fexp2(float x) {
  float r;
  asm("v_exp_f32 %0, %1" : "=v"(r) : "v"(x));
  return r;
}
__device__ __forceinline__ float ftanh(float x) {
  return 1.0f - 2.0f * frcp(fexp2(x * 2.88539008177793f) + 1.0f);
}
__device__ __forceinline__ float fsigmoid(float x) {
  return frcp(1.0f + fexp2(x * -LOG2E));
}
__device__ __forceinline__ float fsoftplus(float x) {
  return (x > 20.0f) ? x : log1pf(__expf(x));
}
__device__ __forceinline__ unsigned short f2b(float x) {
  return __builtin_bit_cast(unsigned short, (__bf16)x);
}
// U col -> W_h row: theta 0-15 -> 0-15; a 16-31 -> 17-32; beta 32-35 -> 33-36; surprise 36 -> 16
__device__ __forceinline__ int permk(int k) {
  if (k < 16) return k;
  if (k < 36) return k + 1;
  return 16;
}

#define WAVE_FENCE() asm volatile("s_waitcnt lgkmcnt(0)" ::: "memory")
#define BLOCK_SYNC()                                        \
  do {                                                      \
    asm volatile("s_waitcnt lgkmcnt(0)" ::: "memory");      \
    __builtin_amdgcn_s_barrier();                           \
    asm volatile("" ::: "memory");                          \
  } while (0)

// ---- Kernel A: per-question item parameters ----
__global__ void precompute_kernel(const float* __restrict__ alpha_raw,
                                  const float* __restrict__ beta_base,
                                  const float* __restrict__ beta_gaps,
                                  float* __restrict__ alpha_q,
                                  float* __restrict__ beta_q,
                                  float* __restrict__ bsumC_q) {
  int tid = blockIdx.x * 256 + threadIdx.x;
  if (tid < (Qn + 1) * 16) alpha_q[tid] = __expf(0.3f * alpha_raw[tid]);
  if (tid < Qn + 1) {
    float base = beta_base[tid];
    float sp0 = fsoftplus(beta_gaps[tid * 3 + 0]);
    float sp1 = fsoftplus(beta_gaps[tid * 3 + 1]);
    float sp2 = fsoftplus(beta_gaps[tid * 3 + 2]);
    float b1 = base, b2 = base + sp0, b3 = b2 + sp1, b4 = b3 + sp2;
    beta_q[tid * 4 + 0] = b1;
    beta_q[tid * 4 + 1] = b2;
    beta_q[tid * 4 + 2] = b3;
    beta_q[tid * 4 + 3] = b4;
    float c1 = b1, c2 = c1 + b2, c3 = c2 + b3, c4 = c3 + b4;
    bsumC_q[tid * 4 + 0] = c1 * LOG2E;
    bsumC_q[tid * 4 + 1] = c2 * LOG2E;
    bsumC_q[tid * 4 + 2] = c3 * LOG2E;
    bsumC_q[tid * 4 + 3] = c4 * LOG2E;
  }
}

// ---- Kernel B: gather alpha/beta output tensors ----
__global__ void itemout_kernel(const int* __restrict__ questions,
                               const float4* __restrict__ alpha_q4,
                               const float4* __restrict__ beta_q4,
                               float4* __restrict__ out_alpha4,
                               float4* __restrict__ out_beta4) {
  int tid = blockIdx.x * 256 + threadIdx.x;
  int pos = tid >> 2, j = tid & 3;
  if (pos >= Bn * Sn) return;
  int q = questions[pos];
  out_alpha4[(size_t)pos * 4 + j] = alpha_q4[(size_t)q * 4 + j];
  if (j == 0) out_beta4[pos] = beta_q4[q];
}

// ---- Kernel C: MFMA scan. 256 threads (4 waves), 16 seqs/block, grid 256 ----
__global__ __launch_bounds__(256, 1) void scan_kernel(
    const float* __restrict__ theta_embed,
    const float* __restrict__ W_h, const float* __restrict__ b_h,
    const float* __restrict__ W_g, const float* __restrict__ b_g,
    const float* __restrict__ W_d, const float* __restrict__ b_d,
    const int* __restrict__ student_ids, const int* __restrict__ questions,
    const int* __restrict__ responses,
    const float* __restrict__ alpha_q, const float4* __restrict__ beta_q4,
    const float4* __restrict__ bsumC_q4,
    float* __restrict__ out_theta, float* __restrict__ out_logits,
    float* __restrict__ out_probs) {
  __shared__ char sU[4 * 16 * UST];   // per-wave U^T: [16 s][64 k] bf16
  __shared__ char sH[2 * 16 * HST];   // H: [16 s][256 j] bf16, dbuf

  const int tid = threadIdx.x;
  const int lane = tid & 63;
  const int wv = tid >> 6;        // 0..3
  const int s = lane & 15;        // seq slot / MFMA N-col (ALL REAL)
  const int g = lane >> 4;        // quad group
  const int bs = blockIdx.x * 16 + s;

  char* uB = sU + wv * (16 * UST);
  {  // zero the used 128B of each U row (pad cols 37..63 stay 0 forever)
    int4 zz = {0, 0, 0, 0};
    char* p = uB + (lane >> 2) * UST + (lane & 3) * 32;
    *(int4*)p = zz;
    *(int4*)(p + 16) = zz;
  }

  // ---- A-fragments: Wh^T slice for this wave's 64 j-rows ----
  bf16x8 whA[4][2];
#pragma unroll
  for (int m = 0; m < 4; ++m) {
    const int j = 64 * wv + 16 * m + s;
#pragma unroll
    for (int kk = 0; kk < 2; ++kk) {
#pragma unroll
      for (int e = 0; e < 8; ++e) {
        const int k = kk * 32 + g * 8 + e;
        float v = 0.0f;
        if (k < 37) v = W_h[permk(k) * 256 + j];
        whA[m][kk][e] = (__bf16)v;
      }
    }
  }
  // ---- A-fragments: [Wg^T ; Wd^T], full K=256, replicated per wave ----
  bf16x8 wgdA[2][8];
#pragma unroll
  for (int m = 0; m < 2; ++m) {
    const float* Wm = m ? W_d : W_g;
#pragma unroll
    for (int kk = 0; kk < 8; ++kk) {
#pragma unroll
      for (int e = 0; e < 8; ++e) {
        const int k = kk * 32 + g * 8 + e;
        wgdA[m][kk][e] = (__bf16)Wm[k * 16 + s];
      }
    }
  }
  f32x4 bias_h[4];
#pragma unroll
  for (int m = 0; m < 4; ++m)
    bias_h[m] = *(const f32x4*)(b_h + 64 * wv + 16 * m + 4 * g);
  const f32x4 bias_g = *(const f32x4*)(b_g + 4 * g);
  const f32x4 bias_d = *(const f32x4*)(b_d + 4 * g);
  const f32x4 zero4 = {0.0f, 0.0f, 0.0f, 0.0f};

  const int* qrow = questions + (size_t)bs * Sn;
  const int* rrow = responses + (size_t)bs * Sn;

  // theta state: th[r] = theta[s][4g+r] (matches Phase-C D layout)
  f32x4 th = *(const f32x4*)(theta_embed +
                             (size_t)student_ids[(size_t)bs * Sn] * 16 + 4 * g);

  int r = rrow[0];
  int q0 = qrow[0];
  float4 a40 = *(const float4*)(alpha_q + (size_t)q0 * 16 + 4 * g);
  float4 bq0 = beta_q4[q0];
  float4 bsC = bsumC_q4[q0];
  int qn = qrow[1], rn = rrow[1];

  // ---- preamble: write t=0's theta/alpha/beta U cols; compute z2(0) ----
  {
    char* ur = uB + s * UST;
    u16x4 thb = {f2b(th.x), f2b(th.y), f2b(th.z), f2b(th.w)};
    *(u16x4*)(ur + 8 * g) = thb;
    u16x4 ab = {f2b(a40.x), f2b(a40.y), f2b(a40.z), f2b(a40.w)};
    *(u16x4*)(ur + 32 + 8 * g) = ab;
    if (g == 0) {
      u16x4 bb = {f2b(bq0.x), f2b(bq0.y), f2b(bq0.z), f2b(bq0.w)};
      *(u16x4*)(ur + 64) = bb;
    }
  }
  float z2;
  {
    float p = a40.x * th.x + a40.y * th.y + a40.z * th.z + a40.w * th.w;
    p += __shfl_xor(p, 16);
    p += __shfl_xor(p, 32);
    z2 = p * LOG2E;
  }

#pragma unroll 2
  for (int t = 0; t < Sn; ++t) {
    // U cols for step t written at end of t-1 (or preamble); z2 = z(t)*log2e ready.
    WAVE_FENCE();
    const bf16x8 ub0 = *(const bf16x8*)(uB + s * UST + 16 * g);  // cols 0-31

    // prefetch t+1 params + t+2 indices
    const float4 a4n = *(const float4*)(alpha_q + (size_t)qn * 16 + 4 * g);
    const float4 bqn = beta_q4[qn];
    const float4 bsCn = bsumC_q4[qn];
    const int t2 = (t + 2 < Sn) ? t + 2 : Sn - 1;
    const int qn2 = qrow[t2];
    const int rn2 = rrow[t2];

    // ---- Phase A: logits (log2 domain, independent FMAs), softmax, surprise ----
    const float lc1 = z2 - bsC.x;
    const float lc2 = fmaf(2.0f, z2, -bsC.y);
    const float lc3 = fmaf(3.0f, z2, -bsC.z);
    const float lc4 = fmaf(4.0f, z2, -bsC.w);
    const float m = fmaxf(fmaxf(fmaxf(lc1, lc2), fmaxf(lc3, lc4)), 0.0f);
    const float e0 = fexp2(-m);
    const float e1 = fexp2(lc1 - m);
    const float e2 = fexp2(lc2 - m);
    const float e3 = fexp2(lc3 - m);
    const float e4 = fexp2(lc4 - m);
    const float inv = frcp(e0 + e1 + e2 + e3 + e4);
    const float expected = (e1 + 2.0f * e2 + 3.0f * e3 + 4.0f * e4) * inv;
    const float surprise = (float)r - expected;

    // ---- Phase B part 1: 4 MFMA on ub0 (independent of surprise) ----
    f32x4 acc0 = __builtin_amdgcn_mfma_f32_16x16x32_bf16(whA[0][0], ub0, bias_h[0], 0, 0, 0);
    f32x4 acc1 = __builtin_amdgcn_mfma_f32_16x16x32_bf16(whA[1][0], ub0, bias_h[1], 0, 0, 0);
    f32x4 acc2 = __builtin_amdgcn_mfma_f32_16x16x32_bf16(whA[2][0], ub0, bias_h[2], 0, 0, 0);
    f32x4 acc3 = __builtin_amdgcn_mfma_f32_16x16x32_bf16(whA[3][0], ub0, bias_h[3], 0, 0, 0);

    // surprise col 36 (the only U write on the softmax chain)
    if (g == 0) *(unsigned short*)(uB + s * UST + 72) = f2b(surprise);

    // ---- outputs: distributed across waves (balanced barrier arrival) ----
    const size_t pos = (size_t)bs * Sn + t;
    if (wv == 0) {
      *(f32x4*)(out_theta + pos * 16 + 4 * g) = th;
    } else if (wv == 1) {
      const float lv =
          (g == 0) ? 0.0f : (g == 1) ? lc1 * LN2 : (g == 2) ? lc2 * LN2 : lc3 * LN2;
      out_logits[pos * 5 + g] = lv;
    } else if (wv == 2) {
      const float pv = ((g == 0) ? e0 : (g == 1) ? e1 : (g == 2) ? e2 : e3) * inv;
      out_probs[pos * 5 + g] = pv;
    } else {
      if (g == 3) {
        out_logits[pos * 5 + 4] = lc4 * LN2;
        out_probs[pos * 5 + 4] = e4 * inv;
      }
    }

    WAVE_FENCE();
    const bf16x8 ub1 = *(const bf16x8*)(uB + s * UST + 64 + 16 * g);  // cols 32-63

    // ---- Phase B part 2 ----
    acc0 = __builtin_amdgcn_mfma_f32_16x16x32_bf16(whA[0][1], ub1, acc0, 0, 0, 0);
    acc1 = __builtin_amdgcn_mfma_f32_16x16x32_bf16(whA[1][1], ub1, acc1, 0, 0, 0);
    acc2 = __builtin_amdgcn_mfma_f32_16x16x32_bf16(whA[2][1], ub1, acc2, 0, 0, 0);
    acc3 = __builtin_amdgcn_mfma_f32_16x16x32_bf16(whA[3][1], ub1, acc3, 0, 0, 0);

    // tanh + pack -> H[s][j] bf16 (lane holds j = 64wv+16m+4g+r)
    char* hB = sH + (t & 1) * (16 * HST);
    {
      char* hr = hB + s * HST + 128 * wv + 8 * g;
      u16x4 h0 = {f2b(ftanh(acc0.x)), f2b(ftanh(acc0.y)), f2b(ftanh(acc0.z)), f2b(ftanh(acc0.w))};
      *(u16x4*)(hr) = h0;
      u16x4 h1 = {f2b(ftanh(acc1.x)), f2b(ftanh(acc1.y)), f2b(ftanh(acc1.z)), f2b(ftanh(acc1.w))};
      *(u16x4*)(hr + 32) = h1;
      u16x4 h2 = {f2b(ftanh(acc2.x)), f2b(ftanh(acc2.y)), f2b(ftanh(acc2.z)), f2b(ftanh(acc2.w))};
      *(u16x4*)(hr + 64) = h2;
      u16x4 h3 = {f2b(ftanh(acc3.x)), f2b(ftanh(acc3.y)), f2b(ftanh(acc3.z)), f2b(ftanh(acc3.w))};
      *(u16x4*)(hr + 96) = h3;
    }
    BLOCK_SYNC();  // the one barrier per step (H is double-buffered)

    // ---- Phase C: [gate;delta]^T = Wgd^T @ H^T, 8 parallel 2-deep chains ----
    const char* hr = hB + s * HST + 16 * g;
    f32x4 ag0 = bias_g, ad0 = bias_d;
    f32x4 ag1 = zero4, ad1 = zero4, ag2 = zero4, ad2 = zero4, ag3 = zero4, ad3 = zero4;
    {
      const bf16x8 hb0 = *(const bf16x8*)(hr);
      const bf16x8 hb1 = *(const bf16x8*)(hr + 64);
      const bf16x8 hb2 = *(const bf16x8*)(hr + 128);
      const bf16x8 hb3 = *(const bf16x8*)(hr + 192);
      ag0 = __builtin_amdgcn_mfma_f32_16x16x32_bf16(wgdA[0][0], hb0, ag0, 0, 0, 0);
      ad0 = __builtin_amdgcn_mfma_f32_16x16x32_bf16(wgdA[1][0], hb0, ad0, 0, 0, 0);
      ag1 = __builtin_amdgcn_mfma_f32_16x16x32_bf16(wgdA[0][1], hb1, ag1, 0, 0, 0);
      ad1 = __builtin_amdgcn_mfma_f32_16x16x32_bf16(wgdA[1][1], hb1, ad1, 0, 0, 0);
      ag2 = __builtin_amdgcn_mfma_f32_16x16x32_bf16(wgdA[0][2], hb2, ag2, 0, 0, 0);
      ad2 = __builtin_amdgcn_mfma_f32_16x16x32_bf16(wgdA[1][2], hb2, ad2, 0, 0, 0);
      ag3 = __builtin_amdgcn_mfma_f32_16x16x32_bf16(wgdA[0][3], hb3, ag3, 0, 0, 0);
      ad3 = __builtin_amdgcn_mfma_f32_16x16x32_bf16(wgdA[1][3], hb3, ad3, 0, 0, 0);
    }
    {
      const bf16x8 hb4 = *(const bf16x8*)(hr + 256);
      const bf16x8 hb5 = *(const bf16x8*)(hr + 320);
      const bf16x8 hb6 = *(const bf16x8*)(hr + 384);
      const bf16x8 hb7 = *(const bf16x8*)(hr + 448);
      ag0 = __builtin_amdgcn_mfma_f32_16x16x32_bf16(wgdA[0][4], hb4, ag0, 0, 0, 0);
      ad0 = __builtin_amdgcn_mfma_f32_16x16x32_bf16(wgdA[1][4], hb4, ad0, 0, 0, 0);
      ag1 = __builtin_amdgcn_mfma_f32_16x16x32_bf16(wgdA[0][5], hb5, ag1, 0, 0, 0);
      ad1 = __builtin_amdgcn_mfma_f32_16x16x32_bf16(wgdA[1][5], hb5, ad1, 0, 0, 0);
      ag2 = __builtin_amdgcn_mfma_f32_16x16x32_bf16(wgdA[0][6], hb6, ag2, 0, 0, 0);
      ad2 = __builtin_amdgcn_mfma_f32_16x16x32_bf16(wgdA[1][6], hb6, ad2, 0, 0, 0);
      ag3 = __builtin_amdgcn_mfma_f32_16x16x32_bf16(wgdA[0][7], hb7, ag3, 0, 0, 0);
      ad3 = __builtin_amdgcn_mfma_f32_16x16x32_bf16(wgdA[1][7], hb7, ad3, 0, 0, 0);
    }
    const f32x4 ag = (ag0 + ag1) + (ag2 + ag3);
    const f32x4 ad = (ad0 + ad1) + (ad2 + ad3);
    // D layout == theta ownership: update in-register, no exchange
    th.x += fsigmoid(ag.x) * ftanh(ad.x);
    th.y += fsigmoid(ag.y) * ftanh(ad.y);
    th.z += fsigmoid(ag.z) * ftanh(ad.z);
    th.w += fsigmoid(ag.w) * ftanh(ad.w);

    // ---- end-of-step: write t+1's U cols; compute z2(t+1) overlapped ----
    {
      char* ur = uB + s * UST;
      u16x4 thb = {f2b(th.x), f2b(th.y), f2b(th.z), f2b(th.w)};
      *(u16x4*)(ur + 8 * g) = thb;
      u16x4 ab = {f2b(a4n.x), f2b(a4n.y), f2b(a4n.z), f2b(a4n.w)};
      *(u16x4*)(ur + 32 + 8 * g) = ab;
      if (g == 0) {
        u16x4 bb = {f2b(bqn.x), f2b(bqn.y), f2b(bqn.z), f2b(bqn.w)};
        *(u16x4*)(ur + 64) = bb;
      }
    }
    {
      float p = a4n.x * th.x + a4n.y * th.y + a4n.z * th.z + a4n.w * th.w;
      p += __shfl_xor(p, 16);
      p += __shfl_xor(p, 32);
      z2 = p * LOG2E;
    }

    // rotate prefetched state
    bsC = bsCn; r = rn;
    qn = qn2; rn = rn2;
  }
}

}  // namespace

extern "C" void kernel_launch(void* const* d_in, const int* in_sizes, int n_in,
                              void* d_out, int out_size, void* d_ws, size_t ws_size,
                              hipStream_t stream) {
  const float* theta_embed = (const float*)d_in[0];
  const float* alpha_raw   = (const float*)d_in[1];
  const float* beta_base   = (const float*)d_in[2];
  const float* beta_gaps   = (const float*)d_in[3];
  const float* W_h = (const float*)d_in[4];
  const float* b_h = (const float*)d_in[5];
  const float* W_g = (const float*)d_in[6];
  const float* b_g = (const float*)d_in[7];
  const float* W_d = (const float*)d_in[8];
  const float* b_d = (const float*)d_in[9];
  const int* student_ids = (const int*)d_in[10];
  const int* questions   = (const int*)d_in[11];
  const int* responses   = (const int*)d_in[12];

  float* out = (float*)d_out;
  float* out_theta  = out;
  float* out_alpha  = out_theta + (size_t)Bn * Sn * 16;
  float* out_beta   = out_alpha + (size_t)Bn * Sn * 16;
  float* out_logits = out_beta  + (size_t)Bn * Sn * 4;
  float* out_probs  = out_logits + (size_t)Bn * Sn * 5;

  float* alpha_q = (float*)d_ws;                      // (Q+1)*16 floats
  float* beta_q  = alpha_q + (size_t)(Qn + 1) * 16;   // (Q+1)*4 floats
  float* bsumC_q = beta_q + (size_t)(Qn + 1) * 4;     // (Q+1)*4 floats

  hipLaunchKernelGGL(precompute_kernel, dim3(63), dim3(256), 0, stream,
                     alpha_raw, beta_base, beta_gaps, alpha_q, beta_q, bsumC_q);
  hipLaunchKernelGGL(itemout_kernel, dim3((Bn * Sn * 4) / 256), dim3(256), 0, stream,
                     questions, (const float4*)alpha_q, (const float4*)beta_q,
                     (float4*)out_alpha, (float4*)out_beta);
  hipLaunchKernelGGL(scan_kernel, dim3(Bn / 16), dim3(256), 0, stream,
                     theta_embed, W_h, b_h, W_g, b_g, W_d, b_d,
                     student_ids, questions, responses,
                     alpha_q, (const float4*)beta_q, (const float4*)bsumC_q,
                     out_theta, out_logits, out_probs);
}

// Round 12
// 697.829 us; speedup vs baseline: 1.3880x; 1.0065x over previous
//
#include <hip/hip_runtime.h>
#include <cstddef>
#include <cstdint>

// DynamicGPCM: B=4096 sequences, S=512 steps, D=16, K=5, H=256, IN=37.
// Outputs (f32, concat): theta(B,S,16) | alpha(B,S,16) | beta(B,S,4) | logits(B,S,5) | probs(B,S,5)
//
// R12 = EXACT R7 skeleton (4 waves x 16 seqs, grid 256, padded LDS strides,
// lgkm-only barrier, 4-deep Phase-C chains, unroll 2) + three strictly-local diffs:
//  1. distributed output stores (w0 theta, w1 logits, w2 probs, w3 tail) - balanced
//     barrier arrival (R7 had one wave doing all stores, arriving late every step).
//  2. log2-domain logits: bsC = cumsum(cumsum beta)*log2e precomputed; lc_k are 4
//     independent FMAs feeding v_exp_f32 (kills the serial l1->l4 chain + 5 muls).
//  3. merged {beta, bsC} 32B item struct: one gather base, two adjacent dwordx4.

namespace {
constexpr int Bn = 4096;
constexpr int Sn = 512;
constexpr int Qn = 1000;

constexpr int UST = 144;   // U row stride (bytes)
constexpr int HST = 528;   // H row stride (bytes)

constexpr float LOG2E = 1.44269504088896f;
constexpr float LN2 = 0.693147180559945f;

typedef __attribute__((ext_vector_type(8))) __bf16 bf16x8;
typedef __attribute__((ext_vector_type(4))) float f32x4;
typedef __attribute__((ext_vector_type(4))) unsigned short u16x4;

__device__ __forceinline__ float frcp(float x) { return __builtin_amdgcn_rcpf(x); }
__device__ __forceinline__ float fexp2(float x) {
  float r;
  asm("v_exp_f32 %0, %1" : "=v"(r) : "v"(x));
  return r;
}
__device__ __forceinline__ float ftanh(float x) {
  return 1.0f - 2.0f * frcp(fexp2(x * 2.88539008177793f) + 1.0f);
}
__device__ __forceinline__ float fsigmoid(float x) {
  return frcp(1.0f + fexp2(x * -LOG2E));
}
__device__ __forceinline__ float fsoftplus(float x) {
  return (x > 20.0f) ? x : log1pf(__expf(x));
}
__device__ __forceinline__ unsigned short f2b(float x) {
  return __builtin_bit_cast(unsigned short, (__bf16)x);
}
// u-column permutation: U cols = [theta 0-15 | a 16-31 | surprise 32 | beta 33-36]
// W_h rows  = [theta 0-15 | surprise 16 | a 17-32 | beta 33-36]
__device__ __forceinline__ int permk(int k) {
  if (k < 16) return k;
  if (k < 32) return k + 1;
  if (k == 32) return 16;
  return k;
}

#define WAVE_FENCE() asm volatile("s_waitcnt lgkmcnt(0)" ::: "memory")
#define BLOCK_SYNC()                                        \
  do {                                                      \
    asm volatile("s_waitcnt lgkmcnt(0)" ::: "memory");      \
    __builtin_amdgcn_s_barrier();                           \
    asm volatile("" ::: "memory");                          \
  } while (0)

// ---- Kernel A: per-question item parameters ----
// itemBB[q] = {b1,b2,b3,b4, c1*L2E, c2*L2E, c3*L2E, c4*L2E}  (32 B)
__global__ void precompute_kernel(const float* __restrict__ alpha_raw,
                                  const float* __restrict__ beta_base,
                                  const float* __restrict__ beta_gaps,
                                  float* __restrict__ alpha_q,
                                  float* __restrict__ itemBB) {
  int tid = blockIdx.x * 256 + threadIdx.x;
  if (tid < (Qn + 1) * 16) alpha_q[tid] = __expf(0.3f * alpha_raw[tid]);
  if (tid < Qn + 1) {
    float base = beta_base[tid];
    float sp0 = fsoftplus(beta_gaps[tid * 3 + 0]);
    float sp1 = fsoftplus(beta_gaps[tid * 3 + 1]);
    float sp2 = fsoftplus(beta_gaps[tid * 3 + 2]);
    float b1 = base, b2 = base + sp0, b3 = b2 + sp1, b4 = b3 + sp2;
    itemBB[tid * 8 + 0] = b1;
    itemBB[tid * 8 + 1] = b2;
    itemBB[tid * 8 + 2] = b3;
    itemBB[tid * 8 + 3] = b4;
    float c1 = b1, c2 = c1 + b2, c3 = c2 + b3, c4 = c3 + b4;
    itemBB[tid * 8 + 4] = c1 * LOG2E;
    itemBB[tid * 8 + 5] = c2 * LOG2E;
    itemBB[tid * 8 + 6] = c3 * LOG2E;
    itemBB[tid * 8 + 7] = c4 * LOG2E;
  }
}

// ---- Kernel B: gather alpha/beta output tensors ----
__global__ void itemout_kernel(const int* __restrict__ questions,
                               const float4* __restrict__ alpha_q4,
                               const float4* __restrict__ itemBB4,
                               float4* __restrict__ out_alpha4,
                               float4* __restrict__ out_beta4) {
  int tid = blockIdx.x * 256 + threadIdx.x;
  int pos = tid >> 2, j = tid & 3;
  if (pos >= Bn * Sn) return;
  int q = questions[pos];
  out_alpha4[(size_t)pos * 4 + j] = alpha_q4[(size_t)q * 4 + j];
  if (j == 0) out_beta4[pos] = itemBB4[q * 2];
}

// ---- Kernel C: MFMA scan. 256 threads (4 waves), 16 seqs/block, grid 256 ----
__global__ __launch_bounds__(256, 1) void scan_kernel(
    const float* __restrict__ theta_embed,
    const float* __restrict__ W_h, const float* __restrict__ b_h,
    const float* __restrict__ W_g, const float* __restrict__ b_g,
    const float* __restrict__ W_d, const float* __restrict__ b_d,
    const int* __restrict__ student_ids, const int* __restrict__ questions,
    const int* __restrict__ responses,
    const float* __restrict__ alpha_q, const float4* __restrict__ itemBB4,
    float* __restrict__ out_theta, float* __restrict__ out_logits,
    float* __restrict__ out_probs) {
  __shared__ char sU[4 * 16 * UST];   // per-wave U^T: [16 s][64 k] bf16, row stride 144B
  __shared__ char sH[2 * 16 * HST];   // H: [16 s][256 j] bf16, row stride 528B, dbuf

  const int tid = threadIdx.x;
  const int lane = tid & 63;
  const int wv = tid >> 6;        // 0..3
  const int s = lane & 15;        // seq slot / MFMA N-col (ALL REAL)
  const int g = lane >> 4;        // quad group
  const int bs = blockIdx.x * 16 + s;

  char* uB = sU + wv * (16 * UST);
  {  // zero the used 128B of each U row (pad cols 37..63 must stay 0 forever)
    int4 zz = {0, 0, 0, 0};
    char* p = uB + (lane >> 2) * UST + (lane & 3) * 32;
    *(int4*)p = zz;
    *(int4*)(p + 16) = zz;
  }

  // ---- A-fragments: Wh^T slice for this wave's 64 j-rows ----
  bf16x8 whA[4][2];
#pragma unroll
  for (int m = 0; m < 4; ++m) {
    const int j = 64 * wv + 16 * m + s;
#pragma unroll
    for (int kk = 0; kk < 2; ++kk) {
#pragma unroll
      for (int e = 0; e < 8; ++e) {
        const int k = kk * 32 + g * 8 + e;
        float v = 0.0f;
        if (k < 37) v = W_h[permk(k) * 256 + j];
        whA[m][kk][e] = (__bf16)v;
      }
    }
  }
  // ---- A-fragments: [Wg^T ; Wd^T], full K=256, replicated per wave ----
  bf16x8 wgdA[2][8];
#pragma unroll
  for (int m = 0; m < 2; ++m) {
    const float* Wm = m ? W_d : W_g;
#pragma unroll
    for (int kk = 0; kk < 8; ++kk) {
#pragma unroll
      for (int e = 0; e < 8; ++e) {
        const int k = kk * 32 + g * 8 + e;
        wgdA[m][kk][e] = (__bf16)Wm[k * 16 + s];
      }
    }
  }
  f32x4 bias_h[4];
#pragma unroll
  for (int m = 0; m < 4; ++m)
    bias_h[m] = *(const f32x4*)(b_h + 64 * wv + 16 * m + 4 * g);
  const f32x4 bias_g = *(const f32x4*)(b_g + 4 * g);
  const f32x4 bias_d = *(const f32x4*)(b_d + 4 * g);
  const f32x4 zero4 = {0.0f, 0.0f, 0.0f, 0.0f};

  const int* qrow = questions + (size_t)bs * Sn;
  const int* rrow = responses + (size_t)bs * Sn;

  // theta state: th[r] = theta[s][4g+r] (matches Phase-C D layout)
  f32x4 th = *(const f32x4*)(theta_embed +
                             (size_t)student_ids[(size_t)bs * Sn] * 16 + 4 * g);

  int r = rrow[0];
  int q0 = qrow[0];
  float4 a4 = *(const float4*)(alpha_q + (size_t)q0 * 16 + 4 * g);
  float4 bq = itemBB4[q0 * 2];
  float4 bsC = itemBB4[q0 * 2 + 1];
  int qn = qrow[1], rn = rrow[1];

#pragma unroll 2
  for (int t = 0; t < Sn; ++t) {
    // prefetch t+1 params + t+2 indices (stay in flight across the lgkm-only barrier)
    const float4 a4n = *(const float4*)(alpha_q + (size_t)qn * 16 + 4 * g);
    const float4 bqn = itemBB4[qn * 2];
    const float4 bsCn = itemBB4[qn * 2 + 1];
    const int t2 = (t + 2 < Sn) ? t + 2 : Sn - 1;
    const int qn2 = qrow[t2];
    const int rn2 = rrow[t2];

    // ---- Phase A: z, softmax (log2 domain), surprise (replicated per wave) ----
    float zp = a4.x * th.x + a4.y * th.y + a4.z * th.z + a4.w * th.w;
    zp += __shfl_xor(zp, 16);
    zp += __shfl_xor(zp, 32);
    const float z2 = zp * LOG2E;

    // independent scaled logits: lc_k = k*z2 - bsC_k
    const float lc1 = z2 - bsC.x;
    const float lc2 = fmaf(2.0f, z2, -bsC.y);
    const float lc3 = fmaf(3.0f, z2, -bsC.z);
    const float lc4 = fmaf(4.0f, z2, -bsC.w);
    const float m = fmaxf(fmaxf(fmaxf(lc1, lc2), fmaxf(lc3, lc4)), 0.0f);
    const float e0 = fexp2(-m);
    const float e1 = fexp2(lc1 - m);
    const float e2 = fexp2(lc2 - m);
    const float e3 = fexp2(lc3 - m);
    const float e4 = fexp2(lc4 - m);
    const float inv = frcp(e0 + e1 + e2 + e3 + e4);
    const float expected = (e1 + 2.0f * e2 + 3.0f * e3 + 4.0f * e4) * inv;
    const float surprise = (float)r - expected;

    // ---- outputs: distributed across waves (balanced barrier arrival) ----
    const size_t pos = (size_t)bs * Sn + t;
    if (wv == 0) {
      *(f32x4*)(out_theta + pos * 16 + 4 * g) = th;
    } else if (wv == 1) {
      const float lv =
          (g == 0) ? 0.0f : (g == 1) ? lc1 * LN2 : (g == 2) ? lc2 * LN2 : lc3 * LN2;
      out_logits[pos * 5 + g] = lv;
    } else if (wv == 2) {
      const float pv = ((g == 0) ? e0 : (g == 1) ? e1 : (g == 2) ? e2 : e3) * inv;
      out_probs[pos * 5 + g] = pv;
    } else {
      if (g == 3) {
        out_logits[pos * 5 + 4] = lc4 * LN2;
        out_probs[pos * 5 + 4] = e4 * inv;
      }
    }

    // ---- write U^T (own wave's copy), bf16 ----
    {
      char* ur = uB + s * UST;
      u16x4 thb = {f2b(th.x), f2b(th.y), f2b(th.z), f2b(th.w)};
      *(u16x4*)(ur + 8 * g) = thb;                       // theta cols 0-15
      u16x4 ab = {f2b(a4.x), f2b(a4.y), f2b(a4.z), f2b(a4.w)};
      *(u16x4*)(ur + 32 + 8 * g) = ab;                   // a cols 16-31
      if (g == 0) {
        u16x4 sb = {f2b(surprise), f2b(bq.x), f2b(bq.y), f2b(bq.z)};
        *(u16x4*)(ur + 64) = sb;                         // cols 32-35
        *(unsigned short*)(ur + 72) = f2b(bq.w);         // col 36
      }
    }
    WAVE_FENCE();

    // ---- Phase B: 64-row slice of H^T = Wh^T @ U^T (8 MFMA, 4 parallel accs) ----
    const bf16x8 ub0 = *(const bf16x8*)(uB + s * UST + 16 * g);
    const bf16x8 ub1 = *(const bf16x8*)(uB + s * UST + 64 + 16 * g);
    f32x4 acc0 = __builtin_amdgcn_mfma_f32_16x16x32_bf16(whA[0][0], ub0, bias_h[0], 0, 0, 0);
    f32x4 acc1 = __builtin_amdgcn_mfma_f32_16x16x32_bf16(whA[1][0], ub0, bias_h[1], 0, 0, 0);
    f32x4 acc2 = __builtin_amdgcn_mfma_f32_16x16x32_bf16(whA[2][0], ub0, bias_h[2], 0, 0, 0);
    f32x4 acc3 = __builtin_amdgcn_mfma_f32_16x16x32_bf16(whA[3][0], ub0, bias_h[3], 0, 0, 0);
    acc0 = __builtin_amdgcn_mfma_f32_16x16x32_bf16(whA[0][1], ub1, acc0, 0, 0, 0);
    acc1 = __builtin_amdgcn_mfma_f32_16x16x32_bf16(whA[1][1], ub1, acc1, 0, 0, 0);
    acc2 = __builtin_amdgcn_mfma_f32_16x16x32_bf16(whA[2][1], ub1, acc2, 0, 0, 0);
    acc3 = __builtin_amdgcn_mfma_f32_16x16x32_bf16(whA[3][1], ub1, acc3, 0, 0, 0);

    // tanh + pack -> H[s][j] bf16 (lane holds j = 64wv+16m+4g+r, r=0..3)
    char* hB = sH + (t & 1) * (16 * HST);
    {
      char* hr = hB + s * HST + 128 * wv + 8 * g;
      u16x4 h0 = {f2b(ftanh(acc0.x)), f2b(ftanh(acc0.y)), f2b(ftanh(acc0.z)), f2b(ftanh(acc0.w))};
      *(u16x4*)(hr) = h0;
      u16x4 h1 = {f2b(ftanh(acc1.x)), f2b(ftanh(acc1.y)), f2b(ftanh(acc1.z)), f2b(ftanh(acc1.w))};
      *(u16x4*)(hr + 32) = h1;
      u16x4 h2 = {f2b(ftanh(acc2.x)), f2b(ftanh(acc2.y)), f2b(ftanh(acc2.z)), f2b(ftanh(acc2.w))};
      *(u16x4*)(hr + 64) = h2;
      u16x4 h3 = {f2b(ftanh(acc3.x)), f2b(ftanh(acc3.y)), f2b(ftanh(acc3.z)), f2b(ftanh(acc3.w))};
      *(u16x4*)(hr + 96) = h3;
    }
    BLOCK_SYNC();  // lgkm-only barrier (H is double-buffered)

    // ---- Phase C: [gate;delta]^T = Wgd^T @ H^T, 4 parallel 4-deep chains ----
    const char* hr = hB + s * HST + 16 * g;
    f32x4 ag0 = bias_g, ad0 = bias_d, ag1 = zero4, ad1 = zero4;
#pragma unroll
    for (int kk = 0; kk < 4; ++kk) {
      const bf16x8 hb = *(const bf16x8*)(hr + 64 * kk);
      ag0 = __builtin_amdgcn_mfma_f32_16x16x32_bf16(wgdA[0][kk], hb, ag0, 0, 0, 0);
      ad0 = __builtin_amdgcn_mfma_f32_16x16x32_bf16(wgdA[1][kk], hb, ad0, 0, 0, 0);
    }
#pragma unroll
    for (int kk = 4; kk < 8; ++kk) {
      const bf16x8 hb = *(const bf16x8*)(hr + 64 * kk);
      ag1 = __builtin_amdgcn_mfma_f32_16x16x32_bf16(wgdA[0][kk], hb, ag1, 0, 0, 0);
      ad1 = __builtin_amdgcn_mfma_f32_16x16x32_bf16(wgdA[1][kk], hb, ad1, 0, 0, 0);
    }
    const f32x4 ag = ag0 + ag1;
    const f32x4 ad = ad0 + ad1;
    // D layout == theta ownership: update in-register, no exchange
    th.x += fsigmoid(ag.x) * ftanh(ad.x);
    th.y += fsigmoid(ag.y) * ftanh(ad.y);
    th.z += fsigmoid(ag.z) * ftanh(ad.z);
    th.w += fsigmoid(ag.w) * ftanh(ad.w);

    // rotate prefetched state
    a4 = a4n; bq = bqn; bsC = bsCn; r = rn;
    qn = qn2; rn = rn2;
  }
}

}  // namespace

extern "C" void kernel_launch(void* const* d_in, const int* in_sizes, int n_in,
                              void* d_out, int out_size, void* d_ws, size_t ws_size,
                              hipStream_t stream) {
  const float* theta_embed = (const float*)d_in[0];
  const float* alpha_raw   = (const float*)d_in[1];
  const float* beta_base   = (const float*)d_in[2];
  const float* beta_gaps   = (const float*)d_in[3];
  const float* W_h = (const float*)d_in[4];
  const float* b_h = (const float*)d_in[5];
  const float* W_g = (const float*)d_in[6];
  const float* b_g = (const float*)d_in[7];
  const float* W_d = (const float*)d_in[8];
  const float* b_d = (const float*)d_in[9];
  const int* student_ids = (const int*)d_in[10];
  const int* questions   = (const int*)d_in[11];
  const int* responses   = (const int*)d_in[12];

  float* out = (float*)d_out;
  float* out_theta  = out;
  float* out_alpha  = out_theta + (size_t)Bn * Sn * 16;
  float* out_beta   = out_alpha + (size_t)Bn * Sn * 16;
  float* out_logits = out_beta  + (size_t)Bn * Sn * 4;
  float* out_probs  = out_logits + (size_t)Bn * Sn * 5;

  float* alpha_q = (float*)d_ws;                      // (Q+1)*16 floats
  float* itemBB  = alpha_q + (size_t)(Qn + 1) * 16;   // (Q+1)*8 floats {beta4, bsC4}

  hipLaunchKernelGGL(precompute_kernel, dim3(63), dim3(256), 0, stream,
                     alpha_raw, beta_base, beta_gaps, alpha_q, itemBB);
  hipLaunchKernelGGL(itemout_kernel, dim3((Bn * Sn * 4) / 256), dim3(256), 0, stream,
                     questions, (const float4*)alpha_q, (const float4*)itemBB,
                     (float4*)out_alpha, (float4*)out_beta);
  hipLaunchKernelGGL(scan_kernel, dim3(Bn / 16), dim3(256), 0, stream,
                     theta_embed, W_h, b_h, W_g, b_g, W_d, b_d,
                     student_ids, questions, responses,
                     alpha_q, (const float4*)itemBB,
                     out_theta, out_logits, out_probs);
}

// Round 13
// 642.676 us; speedup vs baseline: 1.5071x; 1.0858x over previous
//
#include <hip/hip_runtime.h>
#include <cstddef>
#include <cstdint>

// DynamicGPCM: B=4096 sequences, S=512 steps, D=16, K=5, H=256, IN=37.
// Outputs (f32, concat): theta(B,S,16) | alpha(B,S,16) | beta(B,S,4) | logits(B,S,5) | probs(B,S,5)
//
// R13 = EXACT R7 skeleton (4 waves x 16 seqs, grid 256, H 528B rows, lgkm-only
// barrier, rotating stores, 4-deep Phase-C chains, unroll 2) with ONE change:
// the U LDS round-trip is replaced by in-register fragment assembly:
//  - ub0 (u rows 0-31 = theta,alpha): lane (g,s) needs the quads of lanes
//    s+32*(g&1) and +16 -> 4 cvt_pk_bf16 + 8 shfl, issued at loop top,
//    fully overlapped with softmax (no dependence on surprise).
//  - ub1 (u rows 32-63 = [surprise,beta,0..]): lane-local: 3 cvt_pk + g==0 select.
// Deletes 3 LDS writes + full lgkmcnt(0) drain + 2 LDS reads from every step's
// critical chain. sU removed entirely (LDS 26112 -> 16896).

namespace {
constexpr int Bn = 4096;
constexpr int Sn = 512;
constexpr int Qn = 1000;

constexpr int HST = 528;   // H row stride (bytes)

typedef __attribute__((ext_vector_type(8))) __bf16 bf16x8;
typedef __attribute__((ext_vector_type(4))) float f32x4;
typedef __attribute__((ext_vector_type(4))) unsigned short u16x4;
typedef __attribute__((ext_vector_type(4))) unsigned int u32x4;

__device__ __forceinline__ float frcp(float x) { return __builtin_amdgcn_rcpf(x); }
__device__ __forceinline__ float fexp2(float x) {
  float r;
  asm("v_exp_f32 %0, %1" : "=v"(r) : "v"(x));
  return r;
}
// tanh(x) = 1 - 2/(e^{2x}+1);  e^{2x} = 2^{x*2*log2(e)}
__device__ __forceinline__ float ftanh(float x) {
  return 1.0f - 2.0f * frcp(fexp2(x * 2.88539008177793f) + 1.0f);
}
__device__ __forceinline__ float fsigmoid(float x) {
  return frcp(1.0f + fexp2(x * -1.44269504088896f));
}
__device__ __forceinline__ float fsoftplus(float x) {
  return (x > 20.0f) ? x : log1pf(__expf(x));
}
__device__ __forceinline__ unsigned short f2b(float x) {
  return __builtin_bit_cast(unsigned short, (__bf16)x);
}
// dword = {lo16=bf16(a), hi16=bf16(b)}
__device__ __forceinline__ unsigned int cvtpk(float a, float b) {
  unsigned int r;
  asm("v_cvt_pk_bf16_f32 %0, %1, %2" : "=v"(r) : "v"(a), "v"(b));
  return r;
}
// u-column permutation: U cols = [theta 0-15 | a 16-31 | surprise 32 | beta 33-36]
// W_h rows  = [theta 0-15 | surprise 16 | a 17-32 | beta 33-36]
__device__ __forceinline__ int permk(int k) {
  if (k < 16) return k;
  if (k < 32) return k + 1;
  if (k == 32) return 16;
  return k;
}

#define BLOCK_SYNC()                                        \
  do {                                                      \
    asm volatile("s_waitcnt lgkmcnt(0)" ::: "memory");      \
    __builtin_amdgcn_s_barrier();                           \
    asm volatile("" ::: "memory");                          \
  } while (0)

// ---- Kernel A: per-question item parameters ----
__global__ void precompute_kernel(const float* __restrict__ alpha_raw,
                                  const float* __restrict__ beta_base,
                                  const float* __restrict__ beta_gaps,
                                  float* __restrict__ alpha_q,
                                  float* __restrict__ beta_q) {
  int tid = blockIdx.x * 256 + threadIdx.x;
  if (tid < (Qn + 1) * 16) alpha_q[tid] = __expf(0.3f * alpha_raw[tid]);
  if (tid < Qn + 1) {
    float base = beta_base[tid];
    float sp0 = fsoftplus(beta_gaps[tid * 3 + 0]);
    float sp1 = fsoftplus(beta_gaps[tid * 3 + 1]);
    float sp2 = fsoftplus(beta_gaps[tid * 3 + 2]);
    beta_q[tid * 4 + 0] = base;
    beta_q[tid * 4 + 1] = base + sp0;
    beta_q[tid * 4 + 2] = base + sp0 + sp1;
    beta_q[tid * 4 + 3] = base + sp0 + sp1 + sp2;
  }
}

// ---- Kernel B: gather alpha/beta output tensors ----
__global__ void itemout_kernel(const int* __restrict__ questions,
                               const float4* __restrict__ alpha_q4,
                               const float4* __restrict__ beta_q4,
                               float4* __restrict__ out_alpha4,
                               float4* __restrict__ out_beta4) {
  int tid = blockIdx.x * 256 + threadIdx.x;
  int pos = tid >> 2, j = tid & 3;
  if (pos >= Bn * Sn) return;
  int q = questions[pos];
  out_alpha4[(size_t)pos * 4 + j] = alpha_q4[(size_t)q * 4 + j];
  if (j == 0) out_beta4[pos] = beta_q4[q];
}

// ---- Kernel C: MFMA scan. 256 threads (4 waves), 16 seqs/block, grid 256 ----
__global__ __launch_bounds__(256, 1) void scan_kernel(
    const float* __restrict__ theta_embed,
    const float* __restrict__ W_h, const float* __restrict__ b_h,
    const float* __restrict__ W_g, const float* __restrict__ b_g,
    const float* __restrict__ W_d, const float* __restrict__ b_d,
    const int* __restrict__ student_ids, const int* __restrict__ questions,
    const int* __restrict__ responses,
    const float* __restrict__ alpha_q, const float4* __restrict__ beta_q4,
    float* __restrict__ out_theta, float* __restrict__ out_logits,
    float* __restrict__ out_probs) {
  __shared__ char sH[2 * 16 * HST];   // H: [16 s][256 j] bf16, row stride 528B, dbuf

  const int tid = threadIdx.x;
  const int lane = tid & 63;
  const int wv = tid >> 6;        // 0..3
  const int s = lane & 15;        // seq slot / MFMA N-col (ALL REAL)
  const int g = lane >> 4;        // quad group
  const int bs = blockIdx.x * 16 + s;

  // shfl source lanes for ub0 assembly: quads of lanes L0, L0+16
  const int L0 = s + ((g & 1) << 5);
  const int L1 = L0 + 16;

  // ---- A-fragments: Wh^T slice for this wave's 64 j-rows ----
  bf16x8 whA[4][2];
#pragma unroll
  for (int m = 0; m < 4; ++m) {
    const int j = 64 * wv + 16 * m + s;
#pragma unroll
    for (int kk = 0; kk < 2; ++kk) {
#pragma unroll
      for (int e = 0; e < 8; ++e) {
        const int k = kk * 32 + g * 8 + e;
        float v = 0.0f;
        if (k < 37) v = W_h[permk(k) * 256 + j];
        whA[m][kk][e] = (__bf16)v;
      }
    }
  }
  // ---- A-fragments: [Wg^T ; Wd^T], full K=256, replicated per wave ----
  bf16x8 wgdA[2][8];
#pragma unroll
  for (int m = 0; m < 2; ++m) {
    const float* Wm = m ? W_d : W_g;
#pragma unroll
    for (int kk = 0; kk < 8; ++kk) {
#pragma unroll
      for (int e = 0; e < 8; ++e) {
        const int k = kk * 32 + g * 8 + e;
        wgdA[m][kk][e] = (__bf16)Wm[k * 16 + s];
      }
    }
  }
  f32x4 bias_h[4];
#pragma unroll
  for (int m = 0; m < 4; ++m)
    bias_h[m] = *(const f32x4*)(b_h + 64 * wv + 16 * m + 4 * g);
  const f32x4 bias_g = *(const f32x4*)(b_g + 4 * g);
  const f32x4 bias_d = *(const f32x4*)(b_d + 4 * g);
  const f32x4 zero4 = {0.0f, 0.0f, 0.0f, 0.0f};

  const int* qrow = questions + (size_t)bs * Sn;
  const int* rrow = responses + (size_t)bs * Sn;

  // theta state: th[r] = theta[s][4g+r] (matches Phase-C D layout)
  f32x4 th = *(const f32x4*)(theta_embed +
                             (size_t)student_ids[(size_t)bs * Sn] * 16 + 4 * g);

  int r = rrow[0];
  int q0 = qrow[0];
  float4 a4 = *(const float4*)(alpha_q + (size_t)q0 * 16 + 4 * g);
  float4 bq = beta_q4[q0];
  int qn = qrow[1], rn = rrow[1];

#pragma unroll 2
  for (int t = 0; t < Sn; ++t) {
    // ---- ub0 assembly (theta/alpha only - independent of softmax, issues early) ----
    const unsigned int t01 = cvtpk(th.x, th.y), t23 = cvtpk(th.z, th.w);
    const unsigned int a01 = cvtpk(a4.x, a4.y), a23 = cvtpk(a4.z, a4.w);
    const unsigned int bt0 = (unsigned int)__shfl((int)t01, L0);
    const unsigned int bt1 = (unsigned int)__shfl((int)t23, L0);
    const unsigned int bt2 = (unsigned int)__shfl((int)t01, L1);
    const unsigned int bt3 = (unsigned int)__shfl((int)t23, L1);
    const unsigned int ba0 = (unsigned int)__shfl((int)a01, L0);
    const unsigned int ba1 = (unsigned int)__shfl((int)a23, L0);
    const unsigned int ba2 = (unsigned int)__shfl((int)a01, L1);
    const unsigned int ba3 = (unsigned int)__shfl((int)a23, L1);
    const bool isTh = (g < 2);
    u32x4 uv0;
    uv0.x = isTh ? bt0 : ba0;
    uv0.y = isTh ? bt1 : ba1;
    uv0.z = isTh ? bt2 : ba2;
    uv0.w = isTh ? bt3 : ba3;
    const bf16x8 ub0 = __builtin_bit_cast(bf16x8, uv0);

    // prefetch t+1 params + t+2 indices (stay in flight across the lgkm-only barrier)
    const float4 a4n = *(const float4*)(alpha_q + (size_t)qn * 16 + 4 * g);
    const float4 bqn = beta_q4[qn];
    const int t2 = (t + 2 < Sn) ? t + 2 : Sn - 1;
    const int qn2 = qrow[t2];
    const int rn2 = rrow[t2];

    // ---- Phase A (f32): z, softmax, surprise (replicated per wave) ----
    float zp = a4.x * th.x + a4.y * th.y + a4.z * th.z + a4.w * th.w;
    zp += __shfl_xor(zp, 16);
    zp += __shfl_xor(zp, 32);
    const float z = zp;

    const float l1 = z - bq.x;
    const float l2 = l1 + z - bq.y;
    const float l3 = l2 + z - bq.z;
    const float l4 = l3 + z - bq.w;
    const float m = fmaxf(fmaxf(fmaxf(l1, l2), fmaxf(l3, l4)), 0.0f);
    const float e0 = fexp2(-m * 1.44269504088896f);
    const float e1 = fexp2((l1 - m) * 1.44269504088896f);
    const float e2 = fexp2((l2 - m) * 1.44269504088896f);
    const float e3 = fexp2((l3 - m) * 1.44269504088896f);
    const float e4 = fexp2((l4 - m) * 1.44269504088896f);
    const float inv = frcp(e0 + e1 + e2 + e3 + e4);
    const float expected = (e1 + 2.0f * e2 + 3.0f * e3 + 4.0f * e4) * inv;
    const float surprise = (float)r - expected;

    // ---- ub1: lane-local [surprise, beta1..4, 0,0,0] on g==0 lanes only ----
    u32x4 uv1;
    uv1.x = (g == 0) ? cvtpk(surprise, bq.x) : 0u;
    uv1.y = (g == 0) ? cvtpk(bq.y, bq.z) : 0u;
    uv1.z = (g == 0) ? cvtpk(bq.w, 0.0f) : 0u;
    uv1.w = 0u;
    const bf16x8 ub1 = __builtin_bit_cast(bf16x8, uv1);

    // ---- outputs: one wave stores per step (all waves hold identical data) ----
    if (wv == (t & 3)) {
      const size_t pos = (size_t)bs * Sn + t;
      *(f32x4*)(out_theta + pos * 16 + 4 * g) = th;
      const float lv = (g == 0) ? 0.0f : (g == 1) ? l1 : (g == 2) ? l2 : l3;
      const float pv = ((g == 0) ? e0 : (g == 1) ? e1 : (g == 2) ? e2 : e3) * inv;
      out_logits[pos * 5 + g] = lv;
      out_probs[pos * 5 + g] = pv;
      if (g == 3) {
        out_logits[pos * 5 + 4] = l4;
        out_probs[pos * 5 + 4] = e4 * inv;
      }
    }

    // ---- Phase B: 64-row slice of H^T = Wh^T @ U^T (8 MFMA, 4 parallel accs) ----
    f32x4 acc0 = __builtin_amdgcn_mfma_f32_16x16x32_bf16(whA[0][0], ub0, bias_h[0], 0, 0, 0);
    f32x4 acc1 = __builtin_amdgcn_mfma_f32_16x16x32_bf16(whA[1][0], ub0, bias_h[1], 0, 0, 0);
    f32x4 acc2 = __builtin_amdgcn_mfma_f32_16x16x32_bf16(whA[2][0], ub0, bias_h[2], 0, 0, 0);
    f32x4 acc3 = __builtin_amdgcn_mfma_f32_16x16x32_bf16(whA[3][0], ub0, bias_h[3], 0, 0, 0);
    acc0 = __builtin_amdgcn_mfma_f32_16x16x32_bf16(whA[0][1], ub1, acc0, 0, 0, 0);
    acc1 = __builtin_amdgcn_mfma_f32_16x16x32_bf16(whA[1][1], ub1, acc1, 0, 0, 0);
    acc2 = __builtin_amdgcn_mfma_f32_16x16x32_bf16(whA[2][1], ub1, acc2, 0, 0, 0);
    acc3 = __builtin_amdgcn_mfma_f32_16x16x32_bf16(whA[3][1], ub1, acc3, 0, 0, 0);

    // tanh + pack -> H[s][j] bf16 (lane holds j = 64wv+16m+4g+r, r=0..3)
    char* hB = sH + (t & 1) * (16 * HST);
    {
      char* hr = hB + s * HST + 128 * wv + 8 * g;
      u16x4 h0 = {f2b(ftanh(acc0.x)), f2b(ftanh(acc0.y)), f2b(ftanh(acc0.z)), f2b(ftanh(acc0.w))};
      *(u16x4*)(hr) = h0;
      u16x4 h1 = {f2b(ftanh(acc1.x)), f2b(ftanh(acc1.y)), f2b(ftanh(acc1.z)), f2b(ftanh(acc1.w))};
      *(u16x4*)(hr + 32) = h1;
      u16x4 h2 = {f2b(ftanh(acc2.x)), f2b(ftanh(acc2.y)), f2b(ftanh(acc2.z)), f2b(ftanh(acc2.w))};
      *(u16x4*)(hr + 64) = h2;
      u16x4 h3 = {f2b(ftanh(acc3.x)), f2b(ftanh(acc3.y)), f2b(ftanh(acc3.z)), f2b(ftanh(acc3.w))};
      *(u16x4*)(hr + 96) = h3;
    }
    BLOCK_SYNC();  // lgkm-only barrier (H is double-buffered)

    // ---- Phase C: [gate;delta]^T = Wgd^T @ H^T, 4 parallel 4-deep chains ----
    const char* hr = hB + s * HST + 16 * g;
    f32x4 ag0 = bias_g, ad0 = bias_d, ag1 = zero4, ad1 = zero4;
#pragma unroll
    for (int kk = 0; kk < 4; ++kk) {
      const bf16x8 hb = *(const bf16x8*)(hr + 64 * kk);
      ag0 = __builtin_amdgcn_mfma_f32_16x16x32_bf16(wgdA[0][kk], hb, ag0, 0, 0, 0);
      ad0 = __builtin_amdgcn_mfma_f32_16x16x32_bf16(wgdA[1][kk], hb, ad0, 0, 0, 0);
    }
#pragma unroll
    for (int kk = 4; kk < 8; ++kk) {
      const bf16x8 hb = *(const bf16x8*)(hr + 64 * kk);
      ag1 = __builtin_amdgcn_mfma_f32_16x16x32_bf16(wgdA[0][kk], hb, ag1, 0, 0, 0);
      ad1 = __builtin_amdgcn_mfma_f32_16x16x32_bf16(wgdA[1][kk], hb, ad1, 0, 0, 0);
    }
    const f32x4 ag = ag0 + ag1;
    const f32x4 ad = ad0 + ad1;
    // D layout == theta ownership: update in-register, no exchange
    th.x += fsigmoid(ag.x) * ftanh(ad.x);
    th.y += fsigmoid(ag.y) * ftanh(ad.y);
    th.z += fsigmoid(ag.z) * ftanh(ad.z);
    th.w += fsigmoid(ag.w) * ftanh(ad.w);

    // rotate prefetched state
    a4 = a4n; bq = bqn; r = rn;
    qn = qn2; rn = rn2;
  }
}

}  // namespace

extern "C" void kernel_launch(void* const* d_in, const int* in_sizes, int n_in,
                              void* d_out, int out_size, void* d_ws, size_t ws_size,
                              hipStream_t stream) {
  const float* theta_embed = (const float*)d_in[0];
  const float* alpha_raw   = (const float*)d_in[1];
  const float* beta_base   = (const float*)d_in[2];
  const float* beta_gaps   = (const float*)d_in[3];
  const float* W_h = (const float*)d_in[4];
  const float* b_h = (const float*)d_in[5];
  const float* W_g = (const float*)d_in[6];
  const float* b_g = (const float*)d_in[7];
  const float* W_d = (const float*)d_in[8];
  const float* b_d = (const float*)d_in[9];
  const int* student_ids = (const int*)d_in[10];
  const int* questions   = (const int*)d_in[11];
  const int* responses   = (const int*)d_in[12];

  float* out = (float*)d_out;
  float* out_theta  = out;
  float* out_alpha  = out_theta + (size_t)Bn * Sn * 16;
  float* out_beta   = out_alpha + (size_t)Bn * Sn * 16;
  float* out_logits = out_beta  + (size_t)Bn * Sn * 4;
  float* out_probs  = out_logits + (size_t)Bn * Sn * 5;

  float* alpha_q = (float*)d_ws;                     // (Q+1)*16 floats
  float* beta_q  = alpha_q + (size_t)(Qn + 1) * 16;  // (Q+1)*4 floats

  hipLaunchKernelGGL(precompute_kernel, dim3(63), dim3(256), 0, stream,
                     alpha_raw, beta_base, beta_gaps, alpha_q, beta_q);
  hipLaunchKernelGGL(itemout_kernel, dim3((Bn * Sn * 4) / 256), dim3(256), 0, stream,
                     questions, (const float4*)alpha_q, (const float4*)beta_q,
                     (float4*)out_alpha, (float4*)out_beta);
  hipLaunchKernelGGL(scan_kernel, dim3(Bn / 16), dim3(256), 0, stream,
                     theta_embed, W_h, b_h, W_g, b_g, W_d, b_d,
                     student_ids, questions, responses,
                     alpha_q, (const float4*)beta_q,
                     out_theta, out_logits, out_probs);
}

// Round 14
// 607.410 us; speedup vs baseline: 1.5946x; 1.0581x over previous
//
#include <hip/hip_runtime.h>
#include <cstddef>
#include <cstdint>

// DynamicGPCM: B=4096 sequences, S=512 steps, D=16, K=5, H=256, IN=37.
// Outputs (f32, concat): theta(B,S,16) | alpha(B,S,16) | beta(B,S,4) | logits(B,S,5) | probs(B,S,5)
//
// R14 = EXACT revert to R7 (best measured: 609 us). Session map (9 probes):
//   R7 609 | R6 610 | R13 +34 (reg-U via shfl) | R12 +89 (local diffs) |
//   R11 +93 (z-hoist) | R10 +224 (2-group/half-chip) | R9 +257 (mirror slots) |
//   R8 +360 (K-split C). Structure is latency-bound at the problem-forced
//   1 wave/SIMD (4096 seqs x 16 lanes = 1024 waves exactly); every stall-fill
//   or issue-cut neighbor regresses. Locking in the optimum.

namespace {
constexpr int Bn = 4096;
constexpr int Sn = 512;
constexpr int Qn = 1000;

constexpr int UST = 144;   // U row stride in bytes (36 dwords % 32 banks -> rows phase by 4 banks)
constexpr int HST = 528;   // H row stride in bytes (132 dwords % 32 -> rows phase by 4 banks)

typedef __attribute__((ext_vector_type(8))) __bf16 bf16x8;
typedef __attribute__((ext_vector_type(4))) float f32x4;
typedef __attribute__((ext_vector_type(4))) unsigned short u16x4;

__device__ __forceinline__ float frcp(float x) { return __builtin_amdgcn_rcpf(x); }
__device__ __forceinline__ float fexp2(float x) {
  float r;
  asm("v_exp_f32 %0, %1" : "=v"(r) : "v"(x));
  return r;
}
// tanh(x) = 1 - 2/(e^{2x}+1);  e^{2x} = 2^{x*2*log2(e)}
__device__ __forceinline__ float ftanh(float x) {
  return 1.0f - 2.0f * frcp(fexp2(x * 2.88539008177793f) + 1.0f);
}
// sigmoid(x) = 1/(1+e^{-x});  e^{-x} = 2^{-x*log2(e)}
__device__ __forceinline__ float fsigmoid(float x) {
  return frcp(1.0f + fexp2(x * -1.44269504088896f));
}
__device__ __forceinline__ float fsoftplus(float x) {
  return (x > 20.0f) ? x : log1pf(__expf(x));
}
__device__ __forceinline__ unsigned short f2b(float x) {
  return __builtin_bit_cast(unsigned short, (__bf16)x);
}
// u-column permutation: U cols = [theta 0-15 | a 16-31 | surprise 32 | beta 33-36]
// W_h rows  = [theta 0-15 | surprise 16 | a 17-32 | beta 33-36]
__device__ __forceinline__ int permk(int k) {
  if (k < 16) return k;
  if (k < 32) return k + 1;
  if (k == 32) return 16;
  return k;
}

#define WAVE_FENCE() asm volatile("s_waitcnt lgkmcnt(0)" ::: "memory")
// LDS-only barrier: wait own LDS ops, hit the barrier, block hoisting after.
// (No vmcnt(0) drain -> global prefetches stay in flight across the barrier.)
#define BLOCK_SYNC()                                        \
  do {                                                      \
    asm volatile("s_waitcnt lgkmcnt(0)" ::: "memory");      \
    __builtin_amdgcn_s_barrier();                           \
    asm volatile("" ::: "memory");                          \
  } while (0)

// ---- Kernel A: per-question item parameters ----
__global__ void precompute_kernel(const float* __restrict__ alpha_raw,
                                  const float* __restrict__ beta_base,
                                  const float* __restrict__ beta_gaps,
                                  float* __restrict__ alpha_q,
                                  float* __restrict__ beta_q) {
  int tid = blockIdx.x * 256 + threadIdx.x;
  if (tid < (Qn + 1) * 16) alpha_q[tid] = __expf(0.3f * alpha_raw[tid]);
  if (tid < Qn + 1) {
    float base = beta_base[tid];
    float sp0 = fsoftplus(beta_gaps[tid * 3 + 0]);
    float sp1 = fsoftplus(beta_gaps[tid * 3 + 1]);
    float sp2 = fsoftplus(beta_gaps[tid * 3 + 2]);
    beta_q[tid * 4 + 0] = base;
    beta_q[tid * 4 + 1] = base + sp0;
    beta_q[tid * 4 + 2] = base + sp0 + sp1;
    beta_q[tid * 4 + 3] = base + sp0 + sp1 + sp2;
  }
}

// ---- Kernel B: gather alpha/beta output tensors ----
__global__ void itemout_kernel(const int* __restrict__ questions,
                               const float4* __restrict__ alpha_q4,
                               const float4* __restrict__ beta_q4,
                               float4* __restrict__ out_alpha4,
                               float4* __restrict__ out_beta4) {
  int tid = blockIdx.x * 256 + threadIdx.x;
  int pos = tid >> 2, j = tid & 3;
  if (pos >= Bn * Sn) return;
  int q = questions[pos];
  out_alpha4[(size_t)pos * 4 + j] = alpha_q4[(size_t)q * 4 + j];
  if (j == 0) out_beta4[pos] = beta_q4[q];
}

// ---- Kernel C: MFMA scan. 256 threads (4 waves), 16 seqs/block, grid 256 ----
__global__ __launch_bounds__(256, 1) void scan_kernel(
    const float* __restrict__ theta_embed,
    const float* __restrict__ W_h, const float* __restrict__ b_h,
    const float* __restrict__ W_g, const float* __restrict__ b_g,
    const float* __restrict__ W_d, const float* __restrict__ b_d,
    const int* __restrict__ student_ids, const int* __restrict__ questions,
    const int* __restrict__ responses,
    const float* __restrict__ alpha_q, const float4* __restrict__ beta_q4,
    float* __restrict__ out_theta, float* __restrict__ out_logits,
    float* __restrict__ out_probs) {
  __shared__ char sU[4 * 16 * UST];   // per-wave U^T: [16 s][64 k] bf16, row stride 144B
  __shared__ char sH[2 * 16 * HST];   // H: [16 s][256 j] bf16, row stride 528B, dbuf

  const int tid = threadIdx.x;
  const int lane = tid & 63;
  const int wv = tid >> 6;        // 0..3
  const int s = lane & 15;        // seq slot / MFMA N-col (ALL REAL)
  const int g = lane >> 4;        // quad group: k-group (frags) & d-quad (C/D rows)
  const int bs = blockIdx.x * 16 + s;

  char* uB = sU + wv * (16 * UST);
  {  // zero the used 128B of each U row (pad cols 37..63 must stay 0 forever)
    int4 zz = {0, 0, 0, 0};
    char* p = uB + (lane >> 2) * UST + (lane & 3) * 32;
    *(int4*)p = zz;
    *(int4*)(p + 16) = zz;
  }

  // ---- A-fragments: Wh^T slice for this wave's 64 j-rows ----
  bf16x8 whA[4][2];
#pragma unroll
  for (int m = 0; m < 4; ++m) {
    const int j = 64 * wv + 16 * m + s;
#pragma unroll
    for (int kk = 0; kk < 2; ++kk) {
#pragma unroll
      for (int e = 0; e < 8; ++e) {
        const int k = kk * 32 + g * 8 + e;
        float v = 0.0f;
        if (k < 37) v = W_h[permk(k) * 256 + j];
        whA[m][kk][e] = (__bf16)v;
      }
    }
  }
  // ---- A-fragments: [Wg^T ; Wd^T], full K=256, duplicated per wave ----
  bf16x8 wgdA[2][8];
#pragma unroll
  for (int m = 0; m < 2; ++m) {
    const float* Wm = m ? W_d : W_g;
#pragma unroll
    for (int kk = 0; kk < 8; ++kk) {
#pragma unroll
      for (int e = 0; e < 8; ++e) {
        const int k = kk * 32 + g * 8 + e;
        wgdA[m][kk][e] = (__bf16)Wm[k * 16 + s];
      }
    }
  }
  f32x4 bias_h[4];
#pragma unroll
  for (int m = 0; m < 4; ++m)
    bias_h[m] = *(const f32x4*)(b_h + 64 * wv + 16 * m + 4 * g);
  const f32x4 bias_g = *(const f32x4*)(b_g + 4 * g);
  const f32x4 bias_d = *(const f32x4*)(b_d + 4 * g);
  const f32x4 zero4 = {0.0f, 0.0f, 0.0f, 0.0f};

  const int* qrow = questions + (size_t)bs * Sn;
  const int* rrow = responses + (size_t)bs * Sn;

  // theta state: th[r] = theta[s][4g+r] (matches Phase-C D layout)
  f32x4 th = *(const f32x4*)(theta_embed +
                             (size_t)student_ids[(size_t)bs * Sn] * 16 + 4 * g);

  int r = rrow[0];
  int q0 = qrow[0];
  float4 a4 = *(const float4*)(alpha_q + (size_t)q0 * 16 + 4 * g);
  float4 bq = beta_q4[q0];
  int qn = qrow[1], rn = rrow[1];

#pragma unroll 2
  for (int t = 0; t < Sn; ++t) {
    // prefetch t+1 params + t+2 indices (stay in flight across the lgkm-only barrier)
    const float4 a4n = *(const float4*)(alpha_q + (size_t)qn * 16 + 4 * g);
    const float4 bqn = beta_q4[qn];
    const int t2 = (t + 2 < Sn) ? t + 2 : Sn - 1;
    const int qn2 = qrow[t2];
    const int rn2 = rrow[t2];

    // ---- Phase A (f32): z, softmax, surprise (replicated per wave) ----
    float zp = a4.x * th.x + a4.y * th.y + a4.z * th.z + a4.w * th.w;
    zp += __shfl_xor(zp, 16);
    zp += __shfl_xor(zp, 32);
    const float z = zp;

    const float l1 = z - bq.x;
    const float l2 = l1 + z - bq.y;
    const float l3 = l2 + z - bq.z;
    const float l4 = l3 + z - bq.w;
    const float m = fmaxf(fmaxf(fmaxf(l1, l2), fmaxf(l3, l4)), 0.0f);
    const float e0 = fexp2(-m * 1.44269504088896f);
    const float e1 = fexp2((l1 - m) * 1.44269504088896f);
    const float e2 = fexp2((l2 - m) * 1.44269504088896f);
    const float e3 = fexp2((l3 - m) * 1.44269504088896f);
    const float e4 = fexp2((l4 - m) * 1.44269504088896f);
    const float inv = frcp(e0 + e1 + e2 + e3 + e4);
    const float expected = (e1 + 2.0f * e2 + 3.0f * e3 + 4.0f * e4) * inv;
    const float surprise = (float)r - expected;

    // ---- outputs: one wave stores per step (all waves hold identical data) ----
    if (wv == (t & 3)) {
      const size_t pos = (size_t)bs * Sn + t;
      *(f32x4*)(out_theta + pos * 16 + 4 * g) = th;
      const float lv = (g == 0) ? 0.0f : (g == 1) ? l1 : (g == 2) ? l2 : l3;
      const float pv = ((g == 0) ? e0 : (g == 1) ? e1 : (g == 2) ? e2 : e3) * inv;
      out_logits[pos * 5 + g] = lv;
      out_probs[pos * 5 + g] = pv;
      if (g == 3) {
        out_logits[pos * 5 + 4] = l4;
        out_probs[pos * 5 + 4] = e4 * inv;
      }
    }

    // ---- write U^T (own wave's copy), bf16 ----
    {
      char* ur = uB + s * UST;
      u16x4 thb = {f2b(th.x), f2b(th.y), f2b(th.z), f2b(th.w)};
      *(u16x4*)(ur + 8 * g) = thb;                       // theta cols 0-15
      u16x4 ab = {f2b(a4.x), f2b(a4.y), f2b(a4.z), f2b(a4.w)};
      *(u16x4*)(ur + 32 + 8 * g) = ab;                   // a cols 16-31
      if (g == 0) {
        u16x4 sb = {f2b(surprise), f2b(bq.x), f2b(bq.y), f2b(bq.z)};
        *(u16x4*)(ur + 64) = sb;                         // cols 32-35
        *(unsigned short*)(ur + 72) = f2b(bq.w);         // col 36
      }
    }
    WAVE_FENCE();

    // ---- Phase B: 64-row slice of H^T = Wh^T @ U^T (8 MFMA, 4 parallel accs) ----
    const bf16x8 ub0 = *(const bf16x8*)(uB + s * UST + 16 * g);
    const bf16x8 ub1 = *(const bf16x8*)(uB + s * UST + 64 + 16 * g);
    f32x4 acc0 = __builtin_amdgcn_mfma_f32_16x16x32_bf16(whA[0][0], ub0, bias_h[0], 0, 0, 0);
    f32x4 acc1 = __builtin_amdgcn_mfma_f32_16x16x32_bf16(whA[1][0], ub0, bias_h[1], 0, 0, 0);
    f32x4 acc2 = __builtin_amdgcn_mfma_f32_16x16x32_bf16(whA[2][0], ub0, bias_h[2], 0, 0, 0);
    f32x4 acc3 = __builtin_amdgcn_mfma_f32_16x16x32_bf16(whA[3][0], ub0, bias_h[3], 0, 0, 0);
    acc0 = __builtin_amdgcn_mfma_f32_16x16x32_bf16(whA[0][1], ub1, acc0, 0, 0, 0);
    acc1 = __builtin_amdgcn_mfma_f32_16x16x32_bf16(whA[1][1], ub1, acc1, 0, 0, 0);
    acc2 = __builtin_amdgcn_mfma_f32_16x16x32_bf16(whA[2][1], ub1, acc2, 0, 0, 0);
    acc3 = __builtin_amdgcn_mfma_f32_16x16x32_bf16(whA[3][1], ub1, acc3, 0, 0, 0);

    // tanh + pack -> H[s][j] bf16 (lane holds j = 64wv+16m+4g+r, r=0..3)
    char* hB = sH + (t & 1) * (16 * HST);
    {
      char* hr = hB + s * HST + 128 * wv + 8 * g;
      u16x4 h0 = {f2b(ftanh(acc0.x)), f2b(ftanh(acc0.y)), f2b(ftanh(acc0.z)), f2b(ftanh(acc0.w))};
      *(u16x4*)(hr) = h0;
      u16x4 h1 = {f2b(ftanh(acc1.x)), f2b(ftanh(acc1.y)), f2b(ftanh(acc1.z)), f2b(ftanh(acc1.w))};
      *(u16x4*)(hr + 32) = h1;
      u16x4 h2 = {f2b(ftanh(acc2.x)), f2b(ftanh(acc2.y)), f2b(ftanh(acc2.z)), f2b(ftanh(acc2.w))};
      *(u16x4*)(hr + 64) = h2;
      u16x4 h3 = {f2b(ftanh(acc3.x)), f2b(ftanh(acc3.y)), f2b(ftanh(acc3.z)), f2b(ftanh(acc3.w))};
      *(u16x4*)(hr + 96) = h3;
    }
    BLOCK_SYNC();  // lgkm-only barrier (H is double-buffered)

    // ---- Phase C: [gate;delta]^T = Wgd^T @ H^T, 4 parallel 4-deep chains ----
    const char* hr = hB + s * HST + 16 * g;
    f32x4 ag0 = bias_g, ad0 = bias_d, ag1 = zero4, ad1 = zero4;
#pragma unroll
    for (int kk = 0; kk < 4; ++kk) {
      const bf16x8 hb = *(const bf16x8*)(hr + 64 * kk);
      ag0 = __builtin_amdgcn_mfma_f32_16x16x32_bf16(wgdA[0][kk], hb, ag0, 0, 0, 0);
      ad0 = __builtin_amdgcn_mfma_f32_16x16x32_bf16(wgdA[1][kk], hb, ad0, 0, 0, 0);
    }
#pragma unroll
    for (int kk = 4; kk < 8; ++kk) {
      const bf16x8 hb = *(const bf16x8*)(hr + 64 * kk);
      ag1 = __builtin_amdgcn_mfma_f32_16x16x32_bf16(wgdA[0][kk], hb, ag1, 0, 0, 0);
      ad1 = __builtin_amdgcn_mfma_f32_16x16x32_bf16(wgdA[1][kk], hb, ad1, 0, 0, 0);
    }
    const f32x4 ag = ag0 + ag1;
    const f32x4 ad = ad0 + ad1;
    // D layout == theta ownership: update in-register, no exchange
    th.x += fsigmoid(ag.x) * ftanh(ad.x);
    th.y += fsigmoid(ag.y) * ftanh(ad.y);
    th.z += fsigmoid(ag.z) * ftanh(ad.z);
    th.w += fsigmoid(ag.w) * ftanh(ad.w);

    // rotate prefetched state
    a4 = a4n; bq = bqn; r = rn;
    qn = qn2; rn = rn2;
  }
}

}  // namespace

extern "C" void kernel_launch(void* const* d_in, const int* in_sizes, int n_in,
                              void* d_out, int out_size, void* d_ws, size_t ws_size,
                              hipStream_t stream) {
  const float* theta_embed = (const float*)d_in[0];
  const float* alpha_raw   = (const float*)d_in[1];
  const float* beta_base   = (const float*)d_in[2];
  const float* beta_gaps   = (const float*)d_in[3];
  const float* W_h = (const float*)d_in[4];
  const float* b_h = (const float*)d_in[5];
  const float* W_g = (const float*)d_in[6];
  const float* b_g = (const float*)d_in[7];
  const float* W_d = (const float*)d_in[8];
  const float* b_d = (const float*)d_in[9];
  const int* student_ids = (const int*)d_in[10];
  const int* questions   = (const int*)d_in[11];
  const int* responses   = (const int*)d_in[12];

  float* out = (float*)d_out;
  float* out_theta  = out;
  float* out_alpha  = out_theta + (size_t)Bn * Sn * 16;
  float* out_beta   = out_alpha + (size_t)Bn * Sn * 16;
  float* out_logits = out_beta  + (size_t)Bn * Sn * 4;
  float* out_probs  = out_logits + (size_t)Bn * Sn * 5;

  float* alpha_q = (float*)d_ws;                     // (Q+1)*16 floats
  float* beta_q  = alpha_q + (size_t)(Qn + 1) * 16;  // (Q+1)*4 floats

  hipLaunchKernelGGL(precompute_kernel, dim3(63), dim3(256), 0, stream,
                     alpha_raw, beta_base, beta_gaps, alpha_q, beta_q);
  hipLaunchKernelGGL(itemout_kernel, dim3((Bn * Sn * 4) / 256), dim3(256), 0, stream,
                     questions, (const float4*)alpha_q, (const float4*)beta_q,
                     (float4*)out_alpha, (float4*)out_beta);
  hipLaunchKernelGGL(scan_kernel, dim3(Bn / 16), dim3(256), 0, stream,
                     theta_embed, W_h, b_h, W_g, b_g, W_d, b_d,
                     student_ids, questions, responses,
                     alpha_q, (const float4*)beta_q,
                     out_theta, out_logits, out_probs);
}